// Round 6
// baseline (1996.290 us; speedup 1.0000x reference)
//
#include <hip/hip_runtime.h>
#include <hip/hip_bf16.h>
#include <hip/hip_cooperative_groups.h>
#include <math.h>

namespace cg = cooperative_groups;

#define TAU 0.5f

// ---------------------------------------------------------------------------
// CSR build (A and L fused in each phase):
//   histogram -> 3-phase parallel exclusive scan -> scatter.
// deg/next are [2N]: A in [0,N), L in [N,2N). blk arrays [2*nb].
// Edge payload packed int2 {col, float_bits(val)}.
// ---------------------------------------------------------------------------
__global__ void hist2_kernel(const int* __restrict__ rowA,
                             const int* __restrict__ rowL,
                             int* __restrict__ deg, int E, int N) {
    int g = blockIdx.x * 256 + threadIdx.x;
    if (g < E) {
        atomicAdd(&deg[rowA[g]], 1);
    } else {
        int e = g - E;
        if (e < E) atomicAdd(&deg[N + rowL[e]], 1);
    }
}

// Phase 1: per-tile (1024 elements) sums. Grid = 2*nb (A tiles then L tiles).
__global__ void scan_partial_kernel(const int* __restrict__ deg,
                                    int* __restrict__ blk_sum, int n, int nb) {
    int b = blockIdx.x;
    int m = (b >= nb) ? 1 : 0;
    int tile = b - m * nb;
    const int* d = deg + (size_t)m * n;
    int base = tile * 1024;
    int t = threadIdx.x;  // 256
    int s = 0;
#pragma unroll
    for (int j = 0; j < 4; ++j) {
        int i = base + t * 4 + j;
        if (i < n) s += d[i];
    }
    __shared__ int sh[256];
    sh[t] = s;
    __syncthreads();
    for (int off = 128; off; off >>= 1) {
        if (t < off) sh[t] += sh[t + off];
        __syncthreads();
    }
    if (t == 0) blk_sum[b] = sh[0];
}

// Phase 2: 2 blocks (A, L); each scans its nb partials; writes row_ptr[n].
__global__ void scan_blk_kernel(const int* __restrict__ blk_sum,
                                int* __restrict__ blk_off,
                                int* __restrict__ rpnA, int* __restrict__ rpnL,
                                int nb) {
    __shared__ int sh[1024];
    int m = blockIdx.x;
    const int* bs = blk_sum + m * nb;
    int* bo = blk_off + m * nb;
    int t = threadIdx.x;  // 1024
    sh[t] = (t < nb) ? bs[t] : 0;
    __syncthreads();
    for (int off = 1; off < 1024; off <<= 1) {
        int v = (t >= off) ? sh[t - off] : 0;
        __syncthreads();
        sh[t] += v;
        __syncthreads();
    }
    if (t < nb) bo[t] = (t == 0) ? 0 : sh[t - 1];
    if (t == 0) *(m ? rpnL : rpnA) = sh[1023];
}

// Phase 3: per-tile exclusive scan + tile offset; writes row_ptr and next.
__global__ void scan_apply_kernel(const int* __restrict__ deg,
                                  const int* __restrict__ blk_off,
                                  int* __restrict__ rpA, int* __restrict__ rpL,
                                  int* __restrict__ next, int n, int nb) {
    int b = blockIdx.x;
    int m = (b >= nb) ? 1 : 0;
    int tile = b - m * nb;
    const int* d = deg + (size_t)m * n;
    int* rp = m ? rpL : rpA;
    int* nx = next + (size_t)m * n;
    int base = tile * 1024;
    int t = threadIdx.x;  // 256
    int v[4];
    int s = 0;
#pragma unroll
    for (int j = 0; j < 4; ++j) {
        int i = base + t * 4 + j;
        v[j] = (i < n) ? d[i] : 0;
        s += v[j];
    }
    __shared__ int sh[256];
    sh[t] = s;
    __syncthreads();
    for (int off = 1; off < 256; off <<= 1) {
        int x = (t >= off) ? sh[t - off] : 0;
        __syncthreads();
        sh[t] += x;
        __syncthreads();
    }
    int run = blk_off[b] + ((t == 0) ? 0 : sh[t - 1]);
#pragma unroll
    for (int j = 0; j < 4; ++j) {
        int i = base + t * 4 + j;
        if (i < n) { rp[i] = run; nx[i] = run; }
        run += v[j];
    }
}

__global__ void scatter2_kernel(const int* __restrict__ rowA, const int* __restrict__ colA,
                                const float* __restrict__ valA,
                                const int* __restrict__ rowL, const int* __restrict__ colL,
                                const float* __restrict__ valL,
                                int* __restrict__ next,
                                int2* __restrict__ cvA, int2* __restrict__ cvL,
                                int E, int N) {
    int g = blockIdx.x * 256 + threadIdx.x;
    if (g < E) {
        int p = atomicAdd(&next[rowA[g]], 1);
        cvA[p] = make_int2(colA[g], __float_as_int(valA[g]));
    } else {
        int e = g - E;
        if (e < E) {
            int p = atomicAdd(&next[N + rowL[e]], 1);
            cvL[p] = make_int2(colL[e], __float_as_int(valL[e]));
        }
    }
}

// ---------------------------------------------------------------------------
// Fused GNN layer: one wave per row (grid-stride), gather unroll 8.
//   acc[lane] = sum_e val[e] * X[col[e], lane]
//   h[lane]   = sum_k acc[k] * W[lane, k]             (shfl matvec vs LDS W^T)
//   Xn[row]   = X[row] + relu(h)                      (residual, double-buffer)
//   if s: s[row] = dot(Xn[row], Ws)                   (folded score, layer 2)
// ---------------------------------------------------------------------------
__global__ void fused_layer_kernel(const int* __restrict__ row_ptr,
                                   const int2* __restrict__ cv,
                                   const float* __restrict__ X,
                                   const float* __restrict__ W,
                                   float* __restrict__ Xn,
                                   float* __restrict__ s,
                                   const float* __restrict__ Wsv, int n) {
    __shared__ float Wt[64 * 65];
    int tid = threadIdx.x;
    for (int i = tid; i < 4096; i += 256) {
        int j = i >> 6, k = i & 63;     // W[j,k] row-major
        Wt[k * 65 + j] = W[i];          // transpose into LDS, stride 65
    }
    __syncthreads();
    int lane = tid & 63;
    int wv = tid >> 6;
    float wsl = (s != nullptr) ? Wsv[lane] : 0.f;
    int nwaves = gridDim.x * 4;
    for (int row = blockIdx.x * 4 + wv; row < n; row += nwaves) {
        int p = row_ptr[row];
        int end = row_ptr[row + 1];
        float a0 = 0.f, a1 = 0.f, a2 = 0.f, a3 = 0.f;
        for (; p + 8 <= end; p += 8) {
            int2 e0 = cv[p],     e1 = cv[p + 1], e2 = cv[p + 2], e3 = cv[p + 3];
            int2 e4 = cv[p + 4], e5 = cv[p + 5], e6 = cv[p + 6], e7 = cv[p + 7];
            float x0 = X[(size_t)e0.x * 64 + lane];
            float x1 = X[(size_t)e1.x * 64 + lane];
            float x2 = X[(size_t)e2.x * 64 + lane];
            float x3 = X[(size_t)e3.x * 64 + lane];
            float x4 = X[(size_t)e4.x * 64 + lane];
            float x5 = X[(size_t)e5.x * 64 + lane];
            float x6 = X[(size_t)e6.x * 64 + lane];
            float x7 = X[(size_t)e7.x * 64 + lane];
            a0 += __int_as_float(e0.y) * x0;
            a1 += __int_as_float(e1.y) * x1;
            a2 += __int_as_float(e2.y) * x2;
            a3 += __int_as_float(e3.y) * x3;
            a0 += __int_as_float(e4.y) * x4;
            a1 += __int_as_float(e5.y) * x5;
            a2 += __int_as_float(e6.y) * x6;
            a3 += __int_as_float(e7.y) * x7;
        }
        for (; p + 4 <= end; p += 4) {
            int2 e0 = cv[p], e1 = cv[p + 1], e2 = cv[p + 2], e3 = cv[p + 3];
            a0 += __int_as_float(e0.y) * X[(size_t)e0.x * 64 + lane];
            a1 += __int_as_float(e1.y) * X[(size_t)e1.x * 64 + lane];
            a2 += __int_as_float(e2.y) * X[(size_t)e2.x * 64 + lane];
            a3 += __int_as_float(e3.y) * X[(size_t)e3.x * 64 + lane];
        }
        for (; p < end; ++p) {
            int2 e0 = cv[p];
            a0 += __int_as_float(e0.y) * X[(size_t)e0.x * 64 + lane];
        }
        float acc = (a0 + a1) + (a2 + a3);
        float h = 0.f;
#pragma unroll
        for (int k = 0; k < 64; ++k)
            h += __shfl(acc, k, 64) * Wt[k * 65 + lane];
        float xv = X[(size_t)row * 64 + lane] + fmaxf(h, 0.f);
        Xn[(size_t)row * 64 + lane] = xv;
        if (s != nullptr) {
            float d = xv * wsl;
            for (int off = 32; off; off >>= 1) d += __shfl_down(d, off, 64);
            if (lane == 0) s[row] = d;
        }
    }
}

// ---------------------------------------------------------------------------
// Cooperative power iteration: all ITERS iterations + final scale in ONE
// dispatch. 16 lanes per row; per-block norm partials -> grid.sync() ->
// every block reduces the partials (fresh region per iteration; no atomics).
// Normalize folded into next iteration's scale (linearity of L).
// ---------------------------------------------------------------------------
__global__ __launch_bounds__(256, 4)
void power_coop_kernel(const int* __restrict__ row_ptr,
                       const int2* __restrict__ cv,
                       float* __restrict__ va, float* __restrict__ vb,
                       float* __restrict__ part,   // [iters * gridDim.x]
                       float* __restrict__ out,
                       int n, int iters) {
    cg::grid_group grid = cg::this_grid();
    int nb = gridDim.x;
    int tid = threadIdx.x;
    int lane = tid & 63, wvi = tid >> 6;
    int sub = tid >> 4;   // 0..15: row slot within block
    int t = tid & 15;     // lane within 16-wide row team
    __shared__ float red[4];
    __shared__ float s_scale;
    float scale = 1.f;
    float* cur = va;
    float* nxt = vb;
    for (int it = 0; it < iters; ++it) {
        float sq = 0.f;
        for (int row = blockIdx.x * 16 + sub; row < n; row += nb * 16) {
            int p = row_ptr[row] + t;
            int end = row_ptr[row + 1];
            float s0 = 0.f;
            for (; p < end; p += 16) {
                int2 e = cv[p];
                s0 += __int_as_float(e.y) * cur[e.x];
            }
            s0 += __shfl_xor(s0, 8, 16);
            s0 += __shfl_xor(s0, 4, 16);
            s0 += __shfl_xor(s0, 2, 16);
            s0 += __shfl_xor(s0, 1, 16);
            if (t == 0) {
                float sg = (s0 > 0.f) ? 1.f : ((s0 < 0.f) ? -1.f : 0.f);
                float w = s0 * scale - TAU * sg;
                nxt[row] = w;
                sq += w * w;
            }
        }
        __syncthreads();  // red[] safe to overwrite (everyone consumed s_scale)
        for (int off = 32; off; off >>= 1) sq += __shfl_down(sq, off, 64);
        if (lane == 0) red[wvi] = sq;
        __syncthreads();
        if (tid == 0) part[it * nb + blockIdx.x] = red[0] + red[1] + red[2] + red[3];
        grid.sync();
        // every block reduces this iteration's partials
        float x = 0.f;
        for (int i = tid; i < nb; i += 256) x += part[it * nb + i];
        for (int off = 32; off; off >>= 1) x += __shfl_down(x, off, 64);
        __syncthreads();  // red[] reuse
        if (lane == 0) red[wvi] = x;
        __syncthreads();
        if (tid == 0) s_scale = 1.f / fmaxf(sqrtf(red[0] + red[1] + red[2] + red[3]), 1e-12f);
        __syncthreads();
        scale = s_scale;
        float* tmp = cur; cur = nxt; nxt = tmp;
    }
    // cur holds final shrunk vector; scale is its inverse norm.
    for (int i = blockIdx.x * 256 + tid; i < n; i += nb * 256)
        out[i] = cur[i] * scale;
}

extern "C" void kernel_launch(void* const* d_in, const int* in_sizes, int n_in,
                              void* d_out, int out_size, void* d_ws, size_t ws_size,
                              hipStream_t stream) {
    const int* A_row = (const int*)d_in[0];
    const int* A_col = (const int*)d_in[1];
    const float* A_val = (const float*)d_in[2];
    const int* L_row = (const int*)d_in[3];
    const int* L_col = (const int*)d_in[4];
    const float* L_val = (const float*)d_in[5];
    const float* embed = (const float*)d_in[6];
    const float* W1 = (const float*)d_in[7];
    const float* W2 = (const float*)d_in[8];
    const float* Ws = (const float*)d_in[9];
    float* out = (float*)d_out;

    const int E = in_sizes[0];
    const int D = 64;
    const int N = in_sizes[6] / D;
    const int ITERS = 10;
    const int PBLOCKS = 1024;  // cooperative grid: 4 blocks/CU, co-resident

    char* ws = (char*)d_ws;
    size_t off = 0;
    auto carve = [&](size_t bytes) {
        void* p = ws + off;
        off += (bytes + 255) & ~(size_t)255;
        return p;
    };
    float* X0 = (float*)carve((size_t)N * D * sizeof(float));  // 25.6 MB
    float* X1 = (float*)carve((size_t)N * D * sizeof(float));  // 25.6 MB
    int* A_rp = (int*)carve((size_t)(N + 1) * sizeof(int));
    int2* A_cv = (int2*)carve((size_t)E * sizeof(int2));
    int* L_rp = (int*)carve((size_t)(N + 1) * sizeof(int));
    int2* L_cv = (int2*)carve((size_t)E * sizeof(int2));
    int* deg = (int*)carve((size_t)2 * N * sizeof(int));
    int* nxt = (int*)carve((size_t)2 * N * sizeof(int));
    int* blk_sum = (int*)carve(2048 * sizeof(int));
    int* blk_off = (int*)carve(2048 * sizeof(int));
    float* v_cur = (float*)carve((size_t)N * sizeof(float));
    float* v_new = (float*)carve((size_t)N * sizeof(float));
    float* part = (float*)carve((size_t)ITERS * PBLOCKS * sizeof(float));

    int nb = (N + 1023) / 1024;           // scan tiles per matrix
    int h2_blocks = (2 * E + 255) / 256;

    // ---- CSR build (A + L fused per phase) ----
    hipMemsetAsync(deg, 0, (size_t)2 * N * sizeof(int), stream);
    hist2_kernel<<<h2_blocks, 256, 0, stream>>>(A_row, L_row, deg, E, N);
    scan_partial_kernel<<<2 * nb, 256, 0, stream>>>(deg, blk_sum, N, nb);
    scan_blk_kernel<<<2, 1024, 0, stream>>>(blk_sum, blk_off, A_rp + N, L_rp + N, nb);
    scan_apply_kernel<<<2 * nb, 256, 0, stream>>>(deg, blk_off, A_rp, L_rp, nxt, N, nb);
    scatter2_kernel<<<h2_blocks, 256, 0, stream>>>(A_row, A_col, A_val,
                                                   L_row, L_col, L_val,
                                                   nxt, A_cv, L_cv, E, N);

    // ---- two fused residual GNN layers (layer 2 also emits scores) ----
    int fl_blocks = 2048;
    fused_layer_kernel<<<fl_blocks, 256, 0, stream>>>(
        A_rp, A_cv, embed, W1, X0, nullptr, Ws, N);
    fused_layer_kernel<<<fl_blocks, 256, 0, stream>>>(
        A_rp, A_cv, X0, W2, X1, v_cur, Ws, N);

    // ---- power iterations: one cooperative dispatch ----
    int n_i = N, it_i = ITERS;
    void* args[] = {(void*)&L_rp, (void*)&L_cv, (void*)&v_cur, (void*)&v_new,
                    (void*)&part, (void*)&out, (void*)&n_i, (void*)&it_i};
    hipLaunchCooperativeKernel((void*)power_coop_kernel,
                               dim3(PBLOCKS), dim3(256), args, 0, stream);
}

// Round 7
// 1093.525 us; speedup vs baseline: 1.8256x; 1.8256x over previous
//
#include <hip/hip_runtime.h>
#include <hip/hip_bf16.h>
#include <math.h>

#define TAU 0.5f

// ---------------------------------------------------------------------------
// CSR build (A and L fused in each phase):
//   histogram -> 3-phase parallel exclusive scan -> scatter.
// deg/next are [2N]: A in [0,N), L in [N,2N). blk arrays [2*nb].
// Edge payload packed int2 {col, float_bits(val)}.
// ---------------------------------------------------------------------------
__global__ void hist2_kernel(const int* __restrict__ rowA,
                             const int* __restrict__ rowL,
                             int* __restrict__ deg, int E, int N) {
    int g = blockIdx.x * 256 + threadIdx.x;
    if (g < E) {
        atomicAdd(&deg[rowA[g]], 1);
    } else {
        int e = g - E;
        if (e < E) atomicAdd(&deg[N + rowL[e]], 1);
    }
}

// Phase 1: per-tile (1024 elements) sums. Grid = 2*nb (A tiles then L tiles).
__global__ void scan_partial_kernel(const int* __restrict__ deg,
                                    int* __restrict__ blk_sum, int n, int nb) {
    int b = blockIdx.x;
    int m = (b >= nb) ? 1 : 0;
    int tile = b - m * nb;
    const int* d = deg + (size_t)m * n;
    int base = tile * 1024;
    int t = threadIdx.x;  // 256
    int s = 0;
#pragma unroll
    for (int j = 0; j < 4; ++j) {
        int i = base + t * 4 + j;
        if (i < n) s += d[i];
    }
    __shared__ int sh[256];
    sh[t] = s;
    __syncthreads();
    for (int off = 128; off; off >>= 1) {
        if (t < off) sh[t] += sh[t + off];
        __syncthreads();
    }
    if (t == 0) blk_sum[b] = sh[0];
}

// Phase 2: 2 blocks (A, L); each scans its nb partials; writes row_ptr[n].
__global__ void scan_blk_kernel(const int* __restrict__ blk_sum,
                                int* __restrict__ blk_off,
                                int* __restrict__ rpnA, int* __restrict__ rpnL,
                                int nb) {
    __shared__ int sh[1024];
    int m = blockIdx.x;
    const int* bs = blk_sum + m * nb;
    int* bo = blk_off + m * nb;
    int t = threadIdx.x;  // 1024
    sh[t] = (t < nb) ? bs[t] : 0;
    __syncthreads();
    for (int off = 1; off < 1024; off <<= 1) {
        int v = (t >= off) ? sh[t - off] : 0;
        __syncthreads();
        sh[t] += v;
        __syncthreads();
    }
    if (t < nb) bo[t] = (t == 0) ? 0 : sh[t - 1];
    if (t == 0) *(m ? rpnL : rpnA) = sh[1023];
}

// Phase 3: per-tile exclusive scan + tile offset; writes row_ptr and next.
__global__ void scan_apply_kernel(const int* __restrict__ deg,
                                  const int* __restrict__ blk_off,
                                  int* __restrict__ rpA, int* __restrict__ rpL,
                                  int* __restrict__ next, int n, int nb) {
    int b = blockIdx.x;
    int m = (b >= nb) ? 1 : 0;
    int tile = b - m * nb;
    const int* d = deg + (size_t)m * n;
    int* rp = m ? rpL : rpA;
    int* nx = next + (size_t)m * n;
    int base = tile * 1024;
    int t = threadIdx.x;  // 256
    int v[4];
    int s = 0;
#pragma unroll
    for (int j = 0; j < 4; ++j) {
        int i = base + t * 4 + j;
        v[j] = (i < n) ? d[i] : 0;
        s += v[j];
    }
    __shared__ int sh[256];
    sh[t] = s;
    __syncthreads();
    for (int off = 1; off < 256; off <<= 1) {
        int x = (t >= off) ? sh[t - off] : 0;
        __syncthreads();
        sh[t] += x;
        __syncthreads();
    }
    int run = blk_off[b] + ((t == 0) ? 0 : sh[t - 1]);
#pragma unroll
    for (int j = 0; j < 4; ++j) {
        int i = base + t * 4 + j;
        if (i < n) { rp[i] = run; nx[i] = run; }
        run += v[j];
    }
}

__global__ void scatter2_kernel(const int* __restrict__ rowA, const int* __restrict__ colA,
                                const float* __restrict__ valA,
                                const int* __restrict__ rowL, const int* __restrict__ colL,
                                const float* __restrict__ valL,
                                int* __restrict__ next,
                                int2* __restrict__ cvA, int2* __restrict__ cvL,
                                int E, int N) {
    int g = blockIdx.x * 256 + threadIdx.x;
    if (g < E) {
        int p = atomicAdd(&next[rowA[g]], 1);
        cvA[p] = make_int2(colA[g], __float_as_int(valA[g]));
    } else {
        int e = g - E;
        if (e < E) {
            int p = atomicAdd(&next[N + rowL[e]], 1);
            cvL[p] = make_int2(colL[e], __float_as_int(valL[e]));
        }
    }
}

// ---------------------------------------------------------------------------
// Fused GNN layer: one wave per row (grid-stride), gather unroll 8.
//   acc[lane] = sum_e val[e] * X[col[e], lane]
//   h[lane]   = sum_k acc[k] * W[lane, k]             (shfl matvec vs LDS W^T)
//   Xn[row]   = X[row] + relu(h)                      (residual, double-buffer)
//   if s: s[row] = dot(Xn[row], Ws)                   (folded score, layer 2)
// ---------------------------------------------------------------------------
__global__ void fused_layer_kernel(const int* __restrict__ row_ptr,
                                   const int2* __restrict__ cv,
                                   const float* __restrict__ X,
                                   const float* __restrict__ W,
                                   float* __restrict__ Xn,
                                   float* __restrict__ s,
                                   const float* __restrict__ Wsv, int n) {
    __shared__ float Wt[64 * 65];
    int tid = threadIdx.x;
    for (int i = tid; i < 4096; i += 256) {
        int j = i >> 6, k = i & 63;     // W[j,k] row-major
        Wt[k * 65 + j] = W[i];          // transpose into LDS, stride 65
    }
    __syncthreads();
    int lane = tid & 63;
    int wv = tid >> 6;
    float wsl = (s != nullptr) ? Wsv[lane] : 0.f;
    int nwaves = gridDim.x * 4;
    for (int row = blockIdx.x * 4 + wv; row < n; row += nwaves) {
        int p = row_ptr[row];
        int end = row_ptr[row + 1];
        float a0 = 0.f, a1 = 0.f, a2 = 0.f, a3 = 0.f;
        for (; p + 8 <= end; p += 8) {
            int2 e0 = cv[p],     e1 = cv[p + 1], e2 = cv[p + 2], e3 = cv[p + 3];
            int2 e4 = cv[p + 4], e5 = cv[p + 5], e6 = cv[p + 6], e7 = cv[p + 7];
            float x0 = X[(size_t)e0.x * 64 + lane];
            float x1 = X[(size_t)e1.x * 64 + lane];
            float x2 = X[(size_t)e2.x * 64 + lane];
            float x3 = X[(size_t)e3.x * 64 + lane];
            float x4 = X[(size_t)e4.x * 64 + lane];
            float x5 = X[(size_t)e5.x * 64 + lane];
            float x6 = X[(size_t)e6.x * 64 + lane];
            float x7 = X[(size_t)e7.x * 64 + lane];
            a0 += __int_as_float(e0.y) * x0;
            a1 += __int_as_float(e1.y) * x1;
            a2 += __int_as_float(e2.y) * x2;
            a3 += __int_as_float(e3.y) * x3;
            a0 += __int_as_float(e4.y) * x4;
            a1 += __int_as_float(e5.y) * x5;
            a2 += __int_as_float(e6.y) * x6;
            a3 += __int_as_float(e7.y) * x7;
        }
        for (; p + 4 <= end; p += 4) {
            int2 e0 = cv[p], e1 = cv[p + 1], e2 = cv[p + 2], e3 = cv[p + 3];
            a0 += __int_as_float(e0.y) * X[(size_t)e0.x * 64 + lane];
            a1 += __int_as_float(e1.y) * X[(size_t)e1.x * 64 + lane];
            a2 += __int_as_float(e2.y) * X[(size_t)e2.x * 64 + lane];
            a3 += __int_as_float(e3.y) * X[(size_t)e3.x * 64 + lane];
        }
        for (; p < end; ++p) {
            int2 e0 = cv[p];
            a0 += __int_as_float(e0.y) * X[(size_t)e0.x * 64 + lane];
        }
        float acc = (a0 + a1) + (a2 + a3);
        float h = 0.f;
#pragma unroll
        for (int k = 0; k < 64; ++k)
            h += __shfl(acc, k, 64) * Wt[k * 65 + lane];
        float xv = X[(size_t)row * 64 + lane] + fmaxf(h, 0.f);
        Xn[(size_t)row * 64 + lane] = xv;
        if (s != nullptr) {
            float d = xv * wsl;
            for (int off = 32; off; off >>= 1) d += __shfl_down(d, off, 64);
            if (lane == 0) s[row] = d;
        }
    }
}

// ---------------------------------------------------------------------------
// Fused power iteration: 16 lanes per row. Per-iteration launch (kernel
// boundary = cheap grid barrier; coop grid.sync measured ~134us -> never).
//   scale = prev inv-norm, summed from 64 partial slots (wave shuffle).
//   norm written to 64 slots (atomicAdd contention ~98 blocks/slot).
// ---------------------------------------------------------------------------
__global__ void power_iter_kernel(const int* __restrict__ row_ptr,
                                  const int2* __restrict__ cv,
                                  const float* __restrict__ v_in,
                                  float* __restrict__ v_out,
                                  const float* __restrict__ norm_prev,  // 64 slots or null
                                  float* __restrict__ norm_out,         // 64 slots
                                  int n) {
    int lane = threadIdx.x & 63;
    float scale = 1.f;
    if (norm_prev) {
        float x = norm_prev[lane];
#pragma unroll
        for (int off = 32; off; off >>= 1) x += __shfl_xor(x, off, 64);
        scale = 1.f / fmaxf(sqrtf(x), 1e-12f);
    }
    int g = blockIdx.x * 256 + threadIdx.x;
    int row = g >> 4;
    int t = g & 15;
    float sq = 0.f;
    if (row < n) {
        int p = row_ptr[row] + t;
        int end = row_ptr[row + 1];
        float s0 = 0.f;
        for (; p < end; p += 16) {
            int2 e = cv[p];
            s0 += __int_as_float(e.y) * v_in[e.x];
        }
        s0 += __shfl_xor(s0, 8, 16);
        s0 += __shfl_xor(s0, 4, 16);
        s0 += __shfl_xor(s0, 2, 16);
        s0 += __shfl_xor(s0, 1, 16);
        if (t == 0) {
            float sg = (s0 > 0.f) ? 1.f : ((s0 < 0.f) ? -1.f : 0.f);
            float w = s0 * scale - TAU * sg;
            v_out[row] = w;
            sq = w * w;
        }
    }
    for (int off = 32; off; off >>= 1) sq += __shfl_down(sq, off, 64);
    __shared__ float sh[4];
    int wv = threadIdx.x >> 6;
    if (lane == 0) sh[wv] = sq;
    __syncthreads();
    if (threadIdx.x == 0)
        atomicAdd(&norm_out[blockIdx.x & 63], sh[0] + sh[1] + sh[2] + sh[3]);
}

// ---------------------------------------------------------------------------
// out[i] = v[i] * inv_norm (norm from 64 partial slots).
// ---------------------------------------------------------------------------
__global__ void finalize_kernel(const float* __restrict__ v,
                                const float* __restrict__ slots,
                                float* __restrict__ out, int n) {
    int lane = threadIdx.x & 63;
    float x = slots[lane];
#pragma unroll
    for (int off = 32; off; off >>= 1) x += __shfl_xor(x, off, 64);
    float inv = 1.f / fmaxf(sqrtf(x), 1e-12f);
    int i = blockIdx.x * 256 + threadIdx.x;
    if (i < n) out[i] = v[i] * inv;
}

extern "C" void kernel_launch(void* const* d_in, const int* in_sizes, int n_in,
                              void* d_out, int out_size, void* d_ws, size_t ws_size,
                              hipStream_t stream) {
    const int* A_row = (const int*)d_in[0];
    const int* A_col = (const int*)d_in[1];
    const float* A_val = (const float*)d_in[2];
    const int* L_row = (const int*)d_in[3];
    const int* L_col = (const int*)d_in[4];
    const float* L_val = (const float*)d_in[5];
    const float* embed = (const float*)d_in[6];
    const float* W1 = (const float*)d_in[7];
    const float* W2 = (const float*)d_in[8];
    const float* Ws = (const float*)d_in[9];
    float* out = (float*)d_out;

    const int E = in_sizes[0];
    const int D = 64;
    const int N = in_sizes[6] / D;
    const int ITERS = 10;

    char* ws = (char*)d_ws;
    size_t off = 0;
    auto carve = [&](size_t bytes) {
        void* p = ws + off;
        off += (bytes + 255) & ~(size_t)255;
        return p;
    };
    float* X0 = (float*)carve((size_t)N * D * sizeof(float));  // 25.6 MB
    float* X1 = (float*)carve((size_t)N * D * sizeof(float));  // 25.6 MB
    int* A_rp = (int*)carve((size_t)(N + 1) * sizeof(int));
    int2* A_cv = (int2*)carve((size_t)E * sizeof(int2));
    int* L_rp = (int*)carve((size_t)(N + 1) * sizeof(int));
    int2* L_cv = (int2*)carve((size_t)E * sizeof(int2));
    int* deg = (int*)carve((size_t)2 * N * sizeof(int));
    int* nxt = (int*)carve((size_t)2 * N * sizeof(int));
    int* blk_sum = (int*)carve(2048 * sizeof(int));
    int* blk_off = (int*)carve(2048 * sizeof(int));
    float* v_cur = (float*)carve((size_t)N * sizeof(float));
    float* v_new = (float*)carve((size_t)N * sizeof(float));
    float* norms = (float*)carve((size_t)ITERS * 64 * sizeof(float));

    int nb = (N + 1023) / 1024;           // scan tiles per matrix
    int h2_blocks = (2 * E + 255) / 256;
    int n_blocks = (N + 255) / 256;

    // ---- CSR build (A + L fused per phase) ----
    hipMemsetAsync(deg, 0, (size_t)2 * N * sizeof(int), stream);
    hist2_kernel<<<h2_blocks, 256, 0, stream>>>(A_row, L_row, deg, E, N);
    scan_partial_kernel<<<2 * nb, 256, 0, stream>>>(deg, blk_sum, N, nb);
    scan_blk_kernel<<<2, 1024, 0, stream>>>(blk_sum, blk_off, A_rp + N, L_rp + N, nb);
    scan_apply_kernel<<<2 * nb, 256, 0, stream>>>(deg, blk_off, A_rp, L_rp, nxt, N, nb);
    scatter2_kernel<<<h2_blocks, 256, 0, stream>>>(A_row, A_col, A_val,
                                                   L_row, L_col, L_val,
                                                   nxt, A_cv, L_cv, E, N);

    // ---- two fused residual GNN layers (layer 2 also emits scores) ----
    int fl_blocks = 2048;
    fused_layer_kernel<<<fl_blocks, 256, 0, stream>>>(
        A_rp, A_cv, embed, W1, X0, nullptr, Ws, N);
    fused_layer_kernel<<<fl_blocks, 256, 0, stream>>>(
        A_rp, A_cv, X0, W2, X1, v_cur, Ws, N);

    // ---- power iterations (normalize folded; 64-slot norm partials) ----
    hipMemsetAsync(norms, 0, (size_t)ITERS * 64 * sizeof(float), stream);
    int p_blocks = (N * 16 + 255) / 256;
    float* cur = v_cur;
    float* nxt_v = v_new;
    for (int it = 0; it < ITERS; ++it) {
        power_iter_kernel<<<p_blocks, 256, 0, stream>>>(
            L_rp, L_cv, cur, nxt_v,
            it ? (norms + (it - 1) * 64) : nullptr, norms + it * 64, N);
        float* t = cur; cur = nxt_v; nxt_v = t;
    }
    finalize_kernel<<<n_blocks, 256, 0, stream>>>(cur, norms + (ITERS - 1) * 64, out, N);
}

// Round 8
// 960.248 us; speedup vs baseline: 2.0789x; 1.1388x over previous
//
#include <hip/hip_runtime.h>
#include <hip/hip_bf16.h>
#include <math.h>

#define TAU 0.5f
#define BRW 64        // rows per bucket
#define SCAP 255      // per-(bucket,xcd) segment capacity (mean fill ~128)

// ---------------------------------------------------------------------------
// CSR build v2: XCD-local binned sort.
//   init cursors -> bin (per-XCD segments, full-line writes) ->
//   bucket totals -> tiny 3-phase scan -> place (LDS sort per bucket,
//   emits row_ptr + coalesced cv).
// ---------------------------------------------------------------------------
__global__ void init_cur_kernel(int* __restrict__ cur, int K) {
    int k = blockIdx.x * 256 + threadIdx.x;
    if (k < K) cur[k] = k * SCAP;
}

__global__ void bin_kernel(const int* __restrict__ rowA, const int* __restrict__ colA,
                           const float* __restrict__ valA,
                           const int* __restrict__ rowL, const int* __restrict__ colL,
                           const float* __restrict__ valL,
                           int* __restrict__ cur, int2* __restrict__ tmp,
                           int E, int NB) {
    // HW_REG_XCC_ID (id=20, offset 0, size 32): imm = (31<<11)|20 = 63508.
    int xcd = __builtin_amdgcn_s_getreg(63508) & 7;
    int g = blockIdx.x * 256 + threadIdx.x;
    int m = (g >= E) ? 1 : 0;
    int e = g - m * E;
    if (e >= E) return;
    int r = m ? rowL[e] : rowA[e];
    int c = m ? colL[e] : colA[e];
    float v = m ? valL[e] : valA[e];
    int gb = m * NB + (r >> 6);
    int k = gb * 8 + xcd;
    int p = atomicAdd(&cur[k], 1);
    if (p < k * SCAP + SCAP)  // 11-sigma margin; clamp prevents OOB
        tmp[p] = make_int2(c | ((r & 63) << 20), __float_as_int(v));
}

__global__ void bucket_cnt_kernel(const int* __restrict__ cur,
                                  int* __restrict__ bcnt, int NB2) {
    int b = blockIdx.x * 256 + threadIdx.x;
    if (b >= NB2) return;
    int s = 0;
#pragma unroll
    for (int i = 0; i < 8; ++i) {
        int k = b * 8 + i;
        int f = cur[k] - k * SCAP;
        f = (f < 0) ? 0 : ((f > SCAP) ? SCAP : f);
        s += f;
    }
    bcnt[b] = s;
}

// Generic 3-phase exclusive scan over M ints (tiles of 1024).
__global__ void scan_partial_g(const int* __restrict__ in, int* __restrict__ bsum, int M) {
    int base = blockIdx.x * 1024;
    int t = threadIdx.x;  // 256
    int s = 0;
#pragma unroll
    for (int j = 0; j < 4; ++j) {
        int i = base + t * 4 + j;
        if (i < M) s += in[i];
    }
    __shared__ int sh[256];
    sh[t] = s;
    __syncthreads();
    for (int off = 128; off; off >>= 1) {
        if (t < off) sh[t] += sh[t + off];
        __syncthreads();
    }
    if (t == 0) bsum[blockIdx.x] = sh[0];
}

__global__ void scan_blk_g(const int* __restrict__ bsum, int* __restrict__ boffb, int nb) {
    __shared__ int sh[1024];
    int t = threadIdx.x;  // 1024
    sh[t] = (t < nb) ? bsum[t] : 0;
    __syncthreads();
    for (int off = 1; off < 1024; off <<= 1) {
        int v = (t >= off) ? sh[t - off] : 0;
        __syncthreads();
        sh[t] += v;
        __syncthreads();
    }
    if (t < nb) boffb[t] = (t == 0) ? 0 : sh[t - 1];
}

__global__ void scan_apply_g(const int* __restrict__ in, const int* __restrict__ boffb,
                             int* __restrict__ out, int M) {
    int base = blockIdx.x * 1024;
    int t = threadIdx.x;  // 256
    int v[4];
    int s = 0;
#pragma unroll
    for (int j = 0; j < 4; ++j) {
        int i = base + t * 4 + j;
        v[j] = (i < M) ? in[i] : 0;
        s += v[j];
    }
    __shared__ int sh[256];
    sh[t] = s;
    __syncthreads();
    for (int off = 1; off < 256; off <<= 1) {
        int x = (t >= off) ? sh[t - off] : 0;
        __syncthreads();
        sh[t] += x;
        __syncthreads();
    }
    int run = boffb[blockIdx.x] + ((t == 0) ? 0 : sh[t - 1]);
#pragma unroll
    for (int j = 0; j < 4; ++j) {
        int i = base + t * 4 + j;
        if (i < M) out[i] = run;
        run += v[j];
    }
}

// One block per bucket: LDS-sort bucket edges by row, emit row_ptr + cv.
__global__ void place_kernel(const int* __restrict__ cur,
                             const int* __restrict__ boff,
                             const int2* __restrict__ tmp,
                             int* __restrict__ rpA, int* __restrict__ rpL,
                             int2* __restrict__ cvA, int2* __restrict__ cvL,
                             int n, int NB) {
    int b = blockIdx.x;  // 0..2*NB-1
    int m = (b >= NB) ? 1 : 0;
    int lb = b - m * NB;
    int r0 = lb * BRW;
    int r1 = min(r0 + BRW, n);
    int* rp = m ? rpL : rpA;
    int2* cv = m ? cvL : cvA;
    int lbase = m ? boff[NB] : 0;           // L's cv/rp offsets are local
    int p0 = boff[b] - lbase;
    __shared__ int cnt[BRW], curs[BRW];
    __shared__ int fill[8], fbase[8];
    __shared__ int2 stage[8 * SCAP];        // 2040 int2 = 16 KB
    int t = threadIdx.x;
    if (t < BRW) cnt[t] = 0;
    if (t < 8) {
        int k = b * 8 + t;
        int f = cur[k] - k * SCAP;
        fill[t] = (f < 0) ? 0 : ((f > SCAP) ? SCAP : f);
    }
    __syncthreads();
    if (t == 0) {
        int r = 0;
        for (int i = 0; i < 8; ++i) { fbase[i] = r; r += fill[i]; }
    }
    __syncthreads();
    int total = fbase[7] + fill[7];
    for (int i = t; i < total; i += 256) {
        int sgi = 0;
        while (sgi < 7 && i >= fbase[sgi + 1]) ++sgi;
        int2 e = tmp[(size_t)(b * 8 + sgi) * SCAP + (i - fbase[sgi])];
        stage[i] = e;
        atomicAdd(&cnt[(e.x >> 20) & 63], 1);
    }
    __syncthreads();
    if (t == 0) {
        int r = 0;
        for (int i = 0; i < BRW; ++i) { curs[i] = r; r += cnt[i]; }
    }
    __syncthreads();
    if (t < r1 - r0) rp[r0 + t] = p0 + curs[t];
    if (t == 0 && lb == NB - 1) rp[n] = p0 + total;  // sentinel
    __syncthreads();
    for (int i = t; i < total; i += 256) {
        int2 e = stage[i];
        int pos = atomicAdd(&curs[(e.x >> 20) & 63], 1);
        cv[p0 + pos] = make_int2(e.x & 0xFFFFF, e.y);
    }
}

// ---------------------------------------------------------------------------
// Fused GNN layer: one wave per row (grid-stride), gather unroll 8.
// ---------------------------------------------------------------------------
__global__ void fused_layer_kernel(const int* __restrict__ row_ptr,
                                   const int2* __restrict__ cv,
                                   const float* __restrict__ X,
                                   const float* __restrict__ W,
                                   float* __restrict__ Xn,
                                   float* __restrict__ s,
                                   const float* __restrict__ Wsv, int n) {
    __shared__ float Wt[64 * 65];
    int tid = threadIdx.x;
    for (int i = tid; i < 4096; i += 256) {
        int j = i >> 6, k = i & 63;     // W[j,k] row-major
        Wt[k * 65 + j] = W[i];          // transpose into LDS, stride 65
    }
    __syncthreads();
    int lane = tid & 63;
    int wv = tid >> 6;
    float wsl = (s != nullptr) ? Wsv[lane] : 0.f;
    int nwaves = gridDim.x * 4;
    for (int row = blockIdx.x * 4 + wv; row < n; row += nwaves) {
        int p = row_ptr[row];
        int end = row_ptr[row + 1];
        float a0 = 0.f, a1 = 0.f, a2 = 0.f, a3 = 0.f;
        for (; p + 8 <= end; p += 8) {
            int2 e0 = cv[p],     e1 = cv[p + 1], e2 = cv[p + 2], e3 = cv[p + 3];
            int2 e4 = cv[p + 4], e5 = cv[p + 5], e6 = cv[p + 6], e7 = cv[p + 7];
            float x0 = X[(size_t)e0.x * 64 + lane];
            float x1 = X[(size_t)e1.x * 64 + lane];
            float x2 = X[(size_t)e2.x * 64 + lane];
            float x3 = X[(size_t)e3.x * 64 + lane];
            float x4 = X[(size_t)e4.x * 64 + lane];
            float x5 = X[(size_t)e5.x * 64 + lane];
            float x6 = X[(size_t)e6.x * 64 + lane];
            float x7 = X[(size_t)e7.x * 64 + lane];
            a0 += __int_as_float(e0.y) * x0;
            a1 += __int_as_float(e1.y) * x1;
            a2 += __int_as_float(e2.y) * x2;
            a3 += __int_as_float(e3.y) * x3;
            a0 += __int_as_float(e4.y) * x4;
            a1 += __int_as_float(e5.y) * x5;
            a2 += __int_as_float(e6.y) * x6;
            a3 += __int_as_float(e7.y) * x7;
        }
        for (; p + 4 <= end; p += 4) {
            int2 e0 = cv[p], e1 = cv[p + 1], e2 = cv[p + 2], e3 = cv[p + 3];
            a0 += __int_as_float(e0.y) * X[(size_t)e0.x * 64 + lane];
            a1 += __int_as_float(e1.y) * X[(size_t)e1.x * 64 + lane];
            a2 += __int_as_float(e2.y) * X[(size_t)e2.x * 64 + lane];
            a3 += __int_as_float(e3.y) * X[(size_t)e3.x * 64 + lane];
        }
        for (; p < end; ++p) {
            int2 e0 = cv[p];
            a0 += __int_as_float(e0.y) * X[(size_t)e0.x * 64 + lane];
        }
        float acc = (a0 + a1) + (a2 + a3);
        float h = 0.f;
#pragma unroll
        for (int k = 0; k < 64; ++k)
            h += __shfl(acc, k, 64) * Wt[k * 65 + lane];
        float xv = X[(size_t)row * 64 + lane] + fmaxf(h, 0.f);
        Xn[(size_t)row * 64 + lane] = xv;
        if (s != nullptr) {
            float d = xv * wsl;
            for (int off = 32; off; off >>= 1) d += __shfl_down(d, off, 64);
            if (lane == 0) s[row] = d;
        }
    }
}

// ---------------------------------------------------------------------------
// Fused power iteration: 16 lanes per row (per-iteration launch; coop
// grid.sync measured ~134us/iter on this chip -> never again).
// ---------------------------------------------------------------------------
__global__ void power_iter_kernel(const int* __restrict__ row_ptr,
                                  const int2* __restrict__ cv,
                                  const float* __restrict__ v_in,
                                  float* __restrict__ v_out,
                                  const float* __restrict__ norm_prev,  // 64 slots or null
                                  float* __restrict__ norm_out,         // 64 slots
                                  int n) {
    int lane = threadIdx.x & 63;
    float scale = 1.f;
    if (norm_prev) {
        float x = norm_prev[lane];
#pragma unroll
        for (int off = 32; off; off >>= 1) x += __shfl_xor(x, off, 64);
        scale = 1.f / fmaxf(sqrtf(x), 1e-12f);
    }
    int g = blockIdx.x * 256 + threadIdx.x;
    int row = g >> 4;
    int t = g & 15;
    float sq = 0.f;
    if (row < n) {
        int p = row_ptr[row] + t;
        int end = row_ptr[row + 1];
        float s0 = 0.f;
        for (; p < end; p += 16) {
            int2 e = cv[p];
            s0 += __int_as_float(e.y) * v_in[e.x];
        }
        s0 += __shfl_xor(s0, 8, 16);
        s0 += __shfl_xor(s0, 4, 16);
        s0 += __shfl_xor(s0, 2, 16);
        s0 += __shfl_xor(s0, 1, 16);
        if (t == 0) {
            float sg = (s0 > 0.f) ? 1.f : ((s0 < 0.f) ? -1.f : 0.f);
            float w = s0 * scale - TAU * sg;
            v_out[row] = w;
            sq = w * w;
        }
    }
    for (int off = 32; off; off >>= 1) sq += __shfl_down(sq, off, 64);
    __shared__ float sh[4];
    int wv = threadIdx.x >> 6;
    if (lane == 0) sh[wv] = sq;
    __syncthreads();
    if (threadIdx.x == 0)
        atomicAdd(&norm_out[blockIdx.x & 63], sh[0] + sh[1] + sh[2] + sh[3]);
}

__global__ void finalize_kernel(const float* __restrict__ v,
                                const float* __restrict__ slots,
                                float* __restrict__ out, int n) {
    int lane = threadIdx.x & 63;
    float x = slots[lane];
#pragma unroll
    for (int off = 32; off; off >>= 1) x += __shfl_xor(x, off, 64);
    float inv = 1.f / fmaxf(sqrtf(x), 1e-12f);
    int i = blockIdx.x * 256 + threadIdx.x;
    if (i < n) out[i] = v[i] * inv;
}

extern "C" void kernel_launch(void* const* d_in, const int* in_sizes, int n_in,
                              void* d_out, int out_size, void* d_ws, size_t ws_size,
                              hipStream_t stream) {
    const int* A_row = (const int*)d_in[0];
    const int* A_col = (const int*)d_in[1];
    const float* A_val = (const float*)d_in[2];
    const int* L_row = (const int*)d_in[3];
    const int* L_col = (const int*)d_in[4];
    const float* L_val = (const float*)d_in[5];
    const float* embed = (const float*)d_in[6];
    const float* W1 = (const float*)d_in[7];
    const float* W2 = (const float*)d_in[8];
    const float* Ws = (const float*)d_in[9];
    float* out = (float*)d_out;

    const int E = in_sizes[0];
    const int D = 64;
    const int N = in_sizes[6] / D;
    const int ITERS = 10;
    const int NB = (N + BRW - 1) / BRW;   // buckets per matrix (1563)
    const int NB2 = 2 * NB;

    char* ws = (char*)d_ws;
    size_t off = 0;
    auto carve = [&](size_t bytes) {
        void* p = ws + off;
        off += (bytes + 255) & ~(size_t)255;
        return p;
    };
    float* X0 = (float*)carve((size_t)N * D * sizeof(float));  // 25.6 MB
    float* X1 = (float*)carve((size_t)N * D * sizeof(float));  // 25.6 MB
    int2* tmp = (int2*)X0;  // aliases X0+X1 (dead until fused layers);
                            // NB2*8*SCAP*8B = 51.0 MB <= 51.2 MB
    int* A_rp = (int*)carve((size_t)(N + 1) * sizeof(int));
    int2* A_cv = (int2*)carve((size_t)E * sizeof(int2));
    int* L_rp = (int*)carve((size_t)(N + 1) * sizeof(int));
    int2* L_cv = (int2*)carve((size_t)E * sizeof(int2));
    int* cur = (int*)carve((size_t)NB2 * 8 * sizeof(int));
    int* bcnt = (int*)carve((size_t)NB2 * sizeof(int));
    int* boff = (int*)carve((size_t)NB2 * sizeof(int));
    int* bsum = (int*)carve(1024 * sizeof(int));
    int* boffb = (int*)carve(1024 * sizeof(int));
    float* v_cur = (float*)carve((size_t)N * sizeof(float));
    float* v_new = (float*)carve((size_t)N * sizeof(float));
    float* norms = (float*)carve((size_t)ITERS * 64 * sizeof(float));

    int K = NB2 * 8;
    int nbt = (NB2 + 1023) / 1024;  // scan tiles over bucket counts

    // ---- CSR build: XCD-local binned sort ----
    init_cur_kernel<<<(K + 255) / 256, 256, 0, stream>>>(cur, K);
    bin_kernel<<<(2 * E + 255) / 256, 256, 0, stream>>>(
        A_row, A_col, A_val, L_row, L_col, L_val, cur, tmp, E, NB);
    bucket_cnt_kernel<<<(NB2 + 255) / 256, 256, 0, stream>>>(cur, bcnt, NB2);
    scan_partial_g<<<nbt, 256, 0, stream>>>(bcnt, bsum, NB2);
    scan_blk_g<<<1, 1024, 0, stream>>>(bsum, boffb, nbt);
    scan_apply_g<<<nbt, 256, 0, stream>>>(bcnt, boffb, boff, NB2);
    place_kernel<<<NB2, 256, 0, stream>>>(cur, boff, tmp,
                                          A_rp, L_rp, A_cv, L_cv, N, NB);

    // ---- two fused residual GNN layers (layer 2 also emits scores) ----
    int fl_blocks = 2048;
    fused_layer_kernel<<<fl_blocks, 256, 0, stream>>>(
        A_rp, A_cv, embed, W1, X0, nullptr, Ws, N);
    fused_layer_kernel<<<fl_blocks, 256, 0, stream>>>(
        A_rp, A_cv, X0, W2, X1, v_cur, Ws, N);

    // ---- power iterations (normalize folded; 64-slot norm partials) ----
    hipMemsetAsync(norms, 0, (size_t)ITERS * 64 * sizeof(float), stream);
    int p_blocks = (N * 16 + 255) / 256;
    int n_blocks = (N + 255) / 256;
    float* cur_v = v_cur;
    float* nxt_v = v_new;
    for (int it = 0; it < ITERS; ++it) {
        power_iter_kernel<<<p_blocks, 256, 0, stream>>>(
            L_rp, L_cv, cur_v, nxt_v,
            it ? (norms + (it - 1) * 64) : nullptr, norms + it * 64, N);
        float* t = cur_v; cur_v = nxt_v; nxt_v = t;
    }
    finalize_kernel<<<n_blocks, 256, 0, stream>>>(cur_v, norms + (ITERS - 1) * 64, out, N);
}

// Round 9
// 956.086 us; speedup vs baseline: 2.0880x; 1.0044x over previous
//
#include <hip/hip_runtime.h>
#include <hip/hip_bf16.h>
#include <math.h>

#define TAU 0.5f
#define BRW 64         // rows per bucket
#define SSTRIDE 256    // segment stride (entries): 2048 B, line-aligned
#define SCAP 254       // usable capacity (mean fill ~128, +11 sigma)

// ---------------------------------------------------------------------------
// CSR build v3: XCD-local binned sort, per-matrix bin pass (L2-footprint fit).
// ---------------------------------------------------------------------------
__global__ void init_kernel(int* __restrict__ cur, float* __restrict__ norms,
                            int K, int NN) {
    int k = blockIdx.x * 256 + threadIdx.x;
    if (k < K) cur[k] = k * SSTRIDE;
    if (k < NN) norms[k] = 0.f;
}

__global__ void bin_kernel(const int* __restrict__ row, const int* __restrict__ col,
                           const float* __restrict__ val,
                           int* __restrict__ cur, int2* __restrict__ tmp,
                           int E, int kbase) {
    // HW_REG_XCC_ID (id=20, offset 0, size 32): imm = (31<<11)|20 = 63508.
    int xcd = __builtin_amdgcn_s_getreg(63508) & 7;
    int e = blockIdx.x * 256 + threadIdx.x;
    if (e >= E) return;
    int r = row[e];
    int k = (kbase + (r >> 6)) * 8 + xcd;
    int p = atomicAdd(&cur[k], 1);
    if (p < k * SSTRIDE + SCAP)  // 11-sigma margin; clamp prevents OOB
        tmp[p] = make_int2(col[e] | ((r & 63) << 20), __float_as_int(val[e]));
}

// Single block: bucket totals from cursors + exclusive scan over NB2 buckets.
__global__ void scan_fused_kernel(const int* __restrict__ cur,
                                  int* __restrict__ boff, int NB2) {
    __shared__ int sh[1024];
    int t = threadIdx.x;  // 1024
    int b0 = t * 4;
    int v[4];
    int s = 0;
#pragma unroll
    for (int j = 0; j < 4; ++j) {
        int b = b0 + j;
        int c = 0;
        if (b < NB2) {
#pragma unroll
            for (int i = 0; i < 8; ++i) {
                int k = b * 8 + i;
                int f = cur[k] - k * SSTRIDE;
                c += min(max(f, 0), SCAP);
            }
        }
        v[j] = c;
        s += c;
    }
    sh[t] = s;
    __syncthreads();
    for (int off = 1; off < 1024; off <<= 1) {
        int x = (t >= off) ? sh[t - off] : 0;
        __syncthreads();
        sh[t] += x;
        __syncthreads();
    }
    int run = (t == 0) ? 0 : sh[t - 1];
#pragma unroll
    for (int j = 0; j < 4; ++j) {
        int b = b0 + j;
        if (b < NB2) boff[b] = run;
        run += v[j];
    }
}

// One block per bucket: LDS-sort bucket edges by row, emit row_ptr + cv.
__global__ void place_kernel(const int* __restrict__ cur,
                             const int* __restrict__ boff,
                             const int2* __restrict__ tmp,
                             int* __restrict__ rpA, int* __restrict__ rpL,
                             int2* __restrict__ cvA, int2* __restrict__ cvL,
                             int n, int NB) {
    int b = blockIdx.x;  // 0..2*NB-1
    int m = (b >= NB) ? 1 : 0;
    int lb = b - m * NB;
    int r0 = lb * BRW;
    int r1 = min(r0 + BRW, n);
    int* rp = m ? rpL : rpA;
    int2* cv = m ? cvL : cvA;
    int lbase = m ? boff[NB] : 0;           // L's cv/rp offsets are local
    int p0 = boff[b] - lbase;
    __shared__ int cnt[BRW], curs[BRW], rbase[BRW];
    __shared__ int fill[8], fbase[9];
    __shared__ int2 stage[8 * SCAP];        // 2032 int2 = 16.3 KB
    int t = threadIdx.x;
    if (t < BRW) cnt[t] = 0;
    if (t < 8) {
        int k = b * 8 + t;
        int f = cur[k] - k * SSTRIDE;
        fill[t] = min(max(f, 0), SCAP);
    }
    __syncthreads();
    if (t == 0) {
        int r = 0;
#pragma unroll
        for (int i = 0; i < 8; ++i) { fbase[i] = r; r += fill[i]; }
        fbase[8] = r;
    }
    __syncthreads();
    int total = fbase[8];
    // coalesced per-segment load into stage + LDS row histogram
#pragma unroll
    for (int sg = 0; sg < 8; ++sg) {
        int f = fill[sg];
        const int2* src = tmp + (size_t)(b * 8 + sg) * SSTRIDE;
        int fb = fbase[sg];
        for (int i = t; i < f; i += 256) {
            int2 e = src[i];
            stage[fb + i] = e;
            atomicAdd(&cnt[(e.x >> 20) & 63], 1);
        }
    }
    __syncthreads();
    // exclusive scan over 64 row counts (wave 0, shfl ladder)
    if (t < 64) {
        int c = cnt[t];
        int sc = c;
#pragma unroll
        for (int off = 1; off < 64; off <<= 1) {
            int y = __shfl_up(sc, off, 64);
            if (t >= off) sc += y;
        }
        rbase[t] = sc - c;
        curs[t] = sc - c;
    }
    __syncthreads();
    if (t < r1 - r0) rp[r0 + t] = p0 + rbase[t];
    if (t == 0 && lb == NB - 1) rp[n] = p0 + total;  // sentinel
    __syncthreads();
    for (int i = t; i < total; i += 256) {
        int2 e = stage[i];
        int pos = atomicAdd(&curs[(e.x >> 20) & 63], 1);
        cv[p0 + pos] = make_int2(e.x & 0xFFFFF, e.y);
    }
}

// ---------------------------------------------------------------------------
// Fused GNN layer: one wave per row (grid-stride), gather unroll 8.
// ---------------------------------------------------------------------------
__global__ void fused_layer_kernel(const int* __restrict__ row_ptr,
                                   const int2* __restrict__ cv,
                                   const float* __restrict__ X,
                                   const float* __restrict__ W,
                                   float* __restrict__ Xn,
                                   float* __restrict__ s,
                                   const float* __restrict__ Wsv, int n) {
    __shared__ float Wt[64 * 65];
    int tid = threadIdx.x;
    for (int i = tid; i < 4096; i += 256) {
        int j = i >> 6, k = i & 63;     // W[j,k] row-major
        Wt[k * 65 + j] = W[i];          // transpose into LDS, stride 65
    }
    __syncthreads();
    int lane = tid & 63;
    int wv = tid >> 6;
    float wsl = (s != nullptr) ? Wsv[lane] : 0.f;
    int nwaves = gridDim.x * 4;
    for (int row = blockIdx.x * 4 + wv; row < n; row += nwaves) {
        int p = row_ptr[row];
        int end = row_ptr[row + 1];
        float a0 = 0.f, a1 = 0.f, a2 = 0.f, a3 = 0.f;
        for (; p + 8 <= end; p += 8) {
            int2 e0 = cv[p],     e1 = cv[p + 1], e2 = cv[p + 2], e3 = cv[p + 3];
            int2 e4 = cv[p + 4], e5 = cv[p + 5], e6 = cv[p + 6], e7 = cv[p + 7];
            float x0 = X[(size_t)e0.x * 64 + lane];
            float x1 = X[(size_t)e1.x * 64 + lane];
            float x2 = X[(size_t)e2.x * 64 + lane];
            float x3 = X[(size_t)e3.x * 64 + lane];
            float x4 = X[(size_t)e4.x * 64 + lane];
            float x5 = X[(size_t)e5.x * 64 + lane];
            float x6 = X[(size_t)e6.x * 64 + lane];
            float x7 = X[(size_t)e7.x * 64 + lane];
            a0 += __int_as_float(e0.y) * x0;
            a1 += __int_as_float(e1.y) * x1;
            a2 += __int_as_float(e2.y) * x2;
            a3 += __int_as_float(e3.y) * x3;
            a0 += __int_as_float(e4.y) * x4;
            a1 += __int_as_float(e5.y) * x5;
            a2 += __int_as_float(e6.y) * x6;
            a3 += __int_as_float(e7.y) * x7;
        }
        for (; p + 4 <= end; p += 4) {
            int2 e0 = cv[p], e1 = cv[p + 1], e2 = cv[p + 2], e3 = cv[p + 3];
            a0 += __int_as_float(e0.y) * X[(size_t)e0.x * 64 + lane];
            a1 += __int_as_float(e1.y) * X[(size_t)e1.x * 64 + lane];
            a2 += __int_as_float(e2.y) * X[(size_t)e2.x * 64 + lane];
            a3 += __int_as_float(e3.y) * X[(size_t)e3.x * 64 + lane];
        }
        for (; p < end; ++p) {
            int2 e0 = cv[p];
            a0 += __int_as_float(e0.y) * X[(size_t)e0.x * 64 + lane];
        }
        float acc = (a0 + a1) + (a2 + a3);
        float h = 0.f;
#pragma unroll
        for (int k = 0; k < 64; ++k)
            h += __shfl(acc, k, 64) * Wt[k * 65 + lane];
        float xv = X[(size_t)row * 64 + lane] + fmaxf(h, 0.f);
        Xn[(size_t)row * 64 + lane] = xv;
        if (s != nullptr) {
            float d = xv * wsl;
            for (int off = 32; off; off >>= 1) d += __shfl_down(d, off, 64);
            if (lane == 0) s[row] = d;
        }
    }
}

// ---------------------------------------------------------------------------
// Fused power iteration: 16 lanes per row (per-iteration launch; coop
// grid.sync measured ~134us/iter on this chip -> never again).
// ---------------------------------------------------------------------------
__global__ void power_iter_kernel(const int* __restrict__ row_ptr,
                                  const int2* __restrict__ cv,
                                  const float* __restrict__ v_in,
                                  float* __restrict__ v_out,
                                  const float* __restrict__ norm_prev,  // 64 slots or null
                                  float* __restrict__ norm_out,         // 64 slots
                                  int n) {
    int lane = threadIdx.x & 63;
    float scale = 1.f;
    if (norm_prev) {
        float x = norm_prev[lane];
#pragma unroll
        for (int off = 32; off; off >>= 1) x += __shfl_xor(x, off, 64);
        scale = 1.f / fmaxf(sqrtf(x), 1e-12f);
    }
    int g = blockIdx.x * 256 + threadIdx.x;
    int row = g >> 4;
    int t = g & 15;
    float sq = 0.f;
    if (row < n) {
        int p = row_ptr[row] + t;
        int end = row_ptr[row + 1];
        float s0 = 0.f;
        for (; p < end; p += 16) {
            int2 e = cv[p];
            s0 += __int_as_float(e.y) * v_in[e.x];
        }
        s0 += __shfl_xor(s0, 8, 16);
        s0 += __shfl_xor(s0, 4, 16);
        s0 += __shfl_xor(s0, 2, 16);
        s0 += __shfl_xor(s0, 1, 16);
        if (t == 0) {
            float sg = (s0 > 0.f) ? 1.f : ((s0 < 0.f) ? -1.f : 0.f);
            float w = s0 * scale - TAU * sg;
            v_out[row] = w;
            sq = w * w;
        }
    }
    for (int off = 32; off; off >>= 1) sq += __shfl_down(sq, off, 64);
    __shared__ float sh[4];
    int wv = threadIdx.x >> 6;
    if (lane == 0) sh[wv] = sq;
    __syncthreads();
    if (threadIdx.x == 0)
        atomicAdd(&norm_out[blockIdx.x & 63], sh[0] + sh[1] + sh[2] + sh[3]);
}

__global__ void finalize_kernel(const float* __restrict__ v,
                                const float* __restrict__ slots,
                                float* __restrict__ out, int n) {
    int lane = threadIdx.x & 63;
    float x = slots[lane];
#pragma unroll
    for (int off = 32; off; off >>= 1) x += __shfl_xor(x, off, 64);
    float inv = 1.f / fmaxf(sqrtf(x), 1e-12f);
    int i = blockIdx.x * 256 + threadIdx.x;
    if (i < n) out[i] = v[i] * inv;
}

extern "C" void kernel_launch(void* const* d_in, const int* in_sizes, int n_in,
                              void* d_out, int out_size, void* d_ws, size_t ws_size,
                              hipStream_t stream) {
    const int* A_row = (const int*)d_in[0];
    const int* A_col = (const int*)d_in[1];
    const float* A_val = (const float*)d_in[2];
    const int* L_row = (const int*)d_in[3];
    const int* L_col = (const int*)d_in[4];
    const float* L_val = (const float*)d_in[5];
    const float* embed = (const float*)d_in[6];
    const float* W1 = (const float*)d_in[7];
    const float* W2 = (const float*)d_in[8];
    const float* Ws = (const float*)d_in[9];
    float* out = (float*)d_out;

    const int E = in_sizes[0];
    const int D = 64;
    const int N = in_sizes[6] / D;
    const int ITERS = 10;
    const int NB = (N + BRW - 1) / BRW;   // buckets per matrix (1563)
    const int NB2 = 2 * NB;
    const int K = NB2 * 8;                // segment cursors

    char* ws = (char*)d_ws;
    size_t off = 0;
    auto carve = [&](size_t bytes) {
        void* p = ws + off;
        off += (bytes + 255) & ~(size_t)255;
        return p;
    };
    size_t feat_bytes = (size_t)N * D * sizeof(float);
    size_t tmp_bytes = (size_t)K * SSTRIDE * sizeof(int2);
    // X0/X1 and tmp share one region (tmp dead once place ran; X live after)
    char* base = (char*)carve(tmp_bytes > 2 * feat_bytes ? tmp_bytes : 2 * feat_bytes);
    float* X0 = (float*)base;
    float* X1 = (float*)(base + feat_bytes);
    int2* tmp = (int2*)base;
    int* A_rp = (int*)carve((size_t)(N + 1) * sizeof(int));
    int2* A_cv = (int2*)carve((size_t)E * sizeof(int2));
    int* L_rp = (int*)carve((size_t)(N + 1) * sizeof(int));
    int2* L_cv = (int2*)carve((size_t)E * sizeof(int2));
    int* cur = (int*)carve((size_t)K * sizeof(int));
    int* boff = (int*)carve((size_t)NB2 * sizeof(int));
    float* v_cur = (float*)carve((size_t)N * sizeof(float));
    float* v_new = (float*)carve((size_t)N * sizeof(float));
    float* norms = (float*)carve((size_t)ITERS * 64 * sizeof(float));

    int e_blocks = (E + 255) / 256;

    // ---- CSR build: XCD-local binned sort (per-matrix bin for L2 fit) ----
    init_kernel<<<(K + 255) / 256, 256, 0, stream>>>(cur, norms, K, ITERS * 64);
    bin_kernel<<<e_blocks, 256, 0, stream>>>(A_row, A_col, A_val, cur, tmp, E, 0);
    bin_kernel<<<e_blocks, 256, 0, stream>>>(L_row, L_col, L_val, cur, tmp, E, NB);
    scan_fused_kernel<<<1, 1024, 0, stream>>>(cur, boff, NB2);
    place_kernel<<<NB2, 256, 0, stream>>>(cur, boff, tmp,
                                          A_rp, L_rp, A_cv, L_cv, N, NB);

    // ---- two fused residual GNN layers (layer 2 also emits scores) ----
    int fl_blocks = 2048;
    fused_layer_kernel<<<fl_blocks, 256, 0, stream>>>(
        A_rp, A_cv, embed, W1, X0, nullptr, Ws, N);
    fused_layer_kernel<<<fl_blocks, 256, 0, stream>>>(
        A_rp, A_cv, X0, W2, X1, v_cur, Ws, N);

    // ---- power iterations (normalize folded; 64-slot norm partials) ----
    int p_blocks = (N * 16 + 255) / 256;
    int n_blocks = (N + 255) / 256;
    float* cur_v = v_cur;
    float* nxt_v = v_new;
    for (int it = 0; it < ITERS; ++it) {
        power_iter_kernel<<<p_blocks, 256, 0, stream>>>(
            L_rp, L_cv, cur_v, nxt_v,
            it ? (norms + (it - 1) * 64) : nullptr, norms + it * 64, N);
        float* t = cur_v; cur_v = nxt_v; nxt_v = t;
    }
    finalize_kernel<<<n_blocks, 256, 0, stream>>>(cur_v, norms + (ITERS - 1) * 64, out, N);
}

// Round 10
// 934.457 us; speedup vs baseline: 2.1363x; 1.0231x over previous
//
#include <hip/hip_runtime.h>
#include <hip/hip_bf16.h>
#include <math.h>

#define TAU 0.5f
#define BRW 64         // rows per bucket
#define SSTRIDE 256    // segment stride (entries): 2048 B, line-aligned
#define SCAP 254       // usable capacity (mean fill ~128, +11 sigma)

// ---------------------------------------------------------------------------
// CSR build v3: XCD-local binned sort, per-matrix bin pass (L2-footprint fit).
// ---------------------------------------------------------------------------
__global__ void init_kernel(int* __restrict__ cur, float* __restrict__ norms,
                            int K, int NN) {
    int k = blockIdx.x * 256 + threadIdx.x;
    if (k < K) cur[k] = k * SSTRIDE;
    if (k < NN) norms[k] = 0.f;
}

__global__ void bin_kernel(const int* __restrict__ row, const int* __restrict__ col,
                           const float* __restrict__ val,
                           int* __restrict__ cur, int2* __restrict__ tmp,
                           int E, int kbase) {
    // HW_REG_XCC_ID (id=20, offset 0, size 32): imm = (31<<11)|20 = 63508.
    int xcd = __builtin_amdgcn_s_getreg(63508) & 7;
    int e = blockIdx.x * 256 + threadIdx.x;
    if (e >= E) return;
    int r = row[e];
    int k = (kbase + (r >> 6)) * 8 + xcd;
    int p = atomicAdd(&cur[k], 1);
    if (p < k * SSTRIDE + SCAP)  // 11-sigma margin; clamp prevents OOB
        tmp[p] = make_int2(col[e] | ((r & 63) << 20), __float_as_int(val[e]));
}

// Single block: bucket totals from cursors + exclusive scan over NB2 buckets.
__global__ void scan_fused_kernel(const int* __restrict__ cur,
                                  int* __restrict__ boff, int NB2) {
    __shared__ int sh[1024];
    int t = threadIdx.x;  // 1024
    int b0 = t * 4;
    int v[4];
    int s = 0;
#pragma unroll
    for (int j = 0; j < 4; ++j) {
        int b = b0 + j;
        int c = 0;
        if (b < NB2) {
#pragma unroll
            for (int i = 0; i < 8; ++i) {
                int k = b * 8 + i;
                int f = cur[k] - k * SSTRIDE;
                c += min(max(f, 0), SCAP);
            }
        }
        v[j] = c;
        s += c;
    }
    sh[t] = s;
    __syncthreads();
    for (int off = 1; off < 1024; off <<= 1) {
        int x = (t >= off) ? sh[t - off] : 0;
        __syncthreads();
        sh[t] += x;
        __syncthreads();
    }
    int run = (t == 0) ? 0 : sh[t - 1];
#pragma unroll
    for (int j = 0; j < 4; ++j) {
        int b = b0 + j;
        if (b < NB2) boff[b] = run;
        run += v[j];
    }
}

// One block per bucket: LDS-sort bucket edges by row, emit row_ptr + cv.
__global__ void place_kernel(const int* __restrict__ cur,
                             const int* __restrict__ boff,
                             const int2* __restrict__ tmp,
                             int* __restrict__ rpA, int* __restrict__ rpL,
                             int2* __restrict__ cvA, int2* __restrict__ cvL,
                             int n, int NB) {
    int b = blockIdx.x;  // 0..2*NB-1
    int m = (b >= NB) ? 1 : 0;
    int lb = b - m * NB;
    int r0 = lb * BRW;
    int r1 = min(r0 + BRW, n);
    int* rp = m ? rpL : rpA;
    int2* cv = m ? cvL : cvA;
    int lbase = m ? boff[NB] : 0;           // L's cv/rp offsets are local
    int p0 = boff[b] - lbase;
    __shared__ int cnt[BRW], curs[BRW], rbase[BRW];
    __shared__ int fill[8], fbase[9];
    __shared__ int2 stage[8 * SCAP];        // 2032 int2 = 16.3 KB
    int t = threadIdx.x;
    if (t < BRW) cnt[t] = 0;
    if (t < 8) {
        int k = b * 8 + t;
        int f = cur[k] - k * SSTRIDE;
        fill[t] = min(max(f, 0), SCAP);
    }
    __syncthreads();
    if (t == 0) {
        int r = 0;
#pragma unroll
        for (int i = 0; i < 8; ++i) { fbase[i] = r; r += fill[i]; }
        fbase[8] = r;
    }
    __syncthreads();
    int total = fbase[8];
    // coalesced per-segment load into stage + LDS row histogram
#pragma unroll
    for (int sg = 0; sg < 8; ++sg) {
        int f = fill[sg];
        const int2* src = tmp + (size_t)(b * 8 + sg) * SSTRIDE;
        int fb = fbase[sg];
        for (int i = t; i < f; i += 256) {
            int2 e = src[i];
            stage[fb + i] = e;
            atomicAdd(&cnt[(e.x >> 20) & 63], 1);
        }
    }
    __syncthreads();
    // exclusive scan over 64 row counts (wave 0, shfl ladder)
    if (t < 64) {
        int c = cnt[t];
        int sc = c;
#pragma unroll
        for (int off = 1; off < 64; off <<= 1) {
            int y = __shfl_up(sc, off, 64);
            if (t >= off) sc += y;
        }
        rbase[t] = sc - c;
        curs[t] = sc - c;
    }
    __syncthreads();
    if (t < r1 - r0) rp[r0 + t] = p0 + rbase[t];
    if (t == 0 && lb == NB - 1) rp[n] = p0 + total;  // sentinel
    __syncthreads();
    for (int i = t; i < total; i += 256) {
        int2 e = stage[i];
        int pos = atomicAdd(&curs[(e.x >> 20) & 63], 1);
        cv[p0 + pos] = make_int2(e.x & 0xFFFFF, e.y);
    }
}

// ---------------------------------------------------------------------------
// Fused GNN layer v2: one wave per row, half-wave float2 layout.
//   lane = 32*half + sl; lane owns features {2sl, 2sl+1} (float2).
//   Half h processes edges p0+h, p0+h+2, ... -> one VMEM instr fetches TWO
//   edge rows (512 B/wave). Matvec: k-range split by half, float2 broadcasts
//   (36 bpermutes/row vs 64), b64 LDS reads (2-way bank = free).
// ---------------------------------------------------------------------------
__global__ void fused_layer_kernel(const int* __restrict__ row_ptr,
                                   const int2* __restrict__ cv,
                                   const float* __restrict__ X,
                                   const float* __restrict__ W,
                                   float* __restrict__ Xn,
                                   float* __restrict__ s,
                                   const float* __restrict__ Wsv, int n) {
    __shared__ float Wt[64 * 66];       // Wt[k*66 + f] = W[f][k]; even stride
    int tid = threadIdx.x;
    for (int i = tid; i < 4096; i += 256) {
        int j = i >> 6, k = i & 63;     // W[j,k] row-major
        Wt[k * 66 + j] = W[i];
    }
    __syncthreads();
    int lane = tid & 63;
    int sl = lane & 31;
    int half = lane >> 5;
    int wv = tid >> 6;
    float ws0 = 0.f, ws1 = 0.f;
    if (s != nullptr) { ws0 = Wsv[2 * sl]; ws1 = Wsv[2 * sl + 1]; }
    int nwaves = gridDim.x * 4;
    for (int row = blockIdx.x * 4 + wv; row < n; row += nwaves) {
        int p0 = row_ptr[row];
        int end = row_ptr[row + 1];
        // ---- gather: half-split edge streams, 4 pairs unrolled ----
        float2 a0 = {0.f, 0.f}, a1 = {0.f, 0.f}, a2 = {0.f, 0.f}, a3 = {0.f, 0.f};
        int p = p0 + half;
        for (; p + 6 < end; p += 8) {
            int2 e0 = cv[p], e1 = cv[p + 2], e2 = cv[p + 4], e3 = cv[p + 6];
            float2 x0 = *(const float2*)&X[(size_t)e0.x * 64 + 2 * sl];
            float2 x1 = *(const float2*)&X[(size_t)e1.x * 64 + 2 * sl];
            float2 x2 = *(const float2*)&X[(size_t)e2.x * 64 + 2 * sl];
            float2 x3 = *(const float2*)&X[(size_t)e3.x * 64 + 2 * sl];
            float v0 = __int_as_float(e0.y), v1 = __int_as_float(e1.y);
            float v2 = __int_as_float(e2.y), v3 = __int_as_float(e3.y);
            a0.x += v0 * x0.x; a0.y += v0 * x0.y;
            a1.x += v1 * x1.x; a1.y += v1 * x1.y;
            a2.x += v2 * x2.x; a2.y += v2 * x2.y;
            a3.x += v3 * x3.x; a3.y += v3 * x3.y;
        }
        for (; p < end; p += 2) {
            int2 e = cv[p];
            float2 x = *(const float2*)&X[(size_t)e.x * 64 + 2 * sl];
            float v = __int_as_float(e.y);
            a0.x += v * x.x; a0.y += v * x.y;
        }
        float2 acc;
        acc.x = (a0.x + a1.x) + (a2.x + a3.x);
        acc.y = (a0.y + a1.y) + (a2.y + a3.y);
        // combine halves: both halves then hold full AX features {2sl,2sl+1}
        acc.x += __shfl_xor(acc.x, 32, 64);
        acc.y += __shfl_xor(acc.y, 32, 64);
        // ---- matvec: half h covers k in [32h, 32h+32) ----
        float hx = 0.f, hy = 0.f;
        int kbase = 32 * half;
#pragma unroll
        for (int kk = 0; kk < 32; kk += 2) {
            int k = kbase + kk;
            float ax = __shfl(acc.x, k >> 1, 64);  // acc[k]   (k even)
            float ay = __shfl(acc.y, k >> 1, 64);  // acc[k+1]
            float2 w0 = *(const float2*)&Wt[k * 66 + 2 * sl];
            float2 w1 = *(const float2*)&Wt[(k + 1) * 66 + 2 * sl];
            hx += ax * w0.x + ay * w1.x;
            hy += ax * w0.y + ay * w1.y;
        }
        hx += __shfl_xor(hx, 32, 64);
        hy += __shfl_xor(hy, 32, 64);
        // ---- residual + store (half 0 writes) + folded score ----
        float2 xv = *(const float2*)&X[(size_t)row * 64 + 2 * sl];
        float2 o;
        o.x = xv.x + fmaxf(hx, 0.f);
        o.y = xv.y + fmaxf(hy, 0.f);
        if (half == 0) *(float2*)&Xn[(size_t)row * 64 + 2 * sl] = o;
        if (s != nullptr) {
            float d = o.x * ws0 + o.y * ws1;
#pragma unroll
            for (int off = 16; off; off >>= 1) d += __shfl_down(d, off, 32);
            if (lane == 0) s[row] = d;
        }
    }
}

// ---------------------------------------------------------------------------
// Fused power iteration: 16 lanes per row (per-iteration launch; coop
// grid.sync measured ~134us/iter on this chip -> never again).
// ---------------------------------------------------------------------------
__global__ void power_iter_kernel(const int* __restrict__ row_ptr,
                                  const int2* __restrict__ cv,
                                  const float* __restrict__ v_in,
                                  float* __restrict__ v_out,
                                  const float* __restrict__ norm_prev,  // 64 slots or null
                                  float* __restrict__ norm_out,         // 64 slots
                                  int n) {
    int lane = threadIdx.x & 63;
    float scale = 1.f;
    if (norm_prev) {
        float x = norm_prev[lane];
#pragma unroll
        for (int off = 32; off; off >>= 1) x += __shfl_xor(x, off, 64);
        scale = 1.f / fmaxf(sqrtf(x), 1e-12f);
    }
    int g = blockIdx.x * 256 + threadIdx.x;
    int row = g >> 4;
    int t = g & 15;
    float sq = 0.f;
    if (row < n) {
        int p = row_ptr[row] + t;
        int end = row_ptr[row + 1];
        float s0 = 0.f;
        for (; p < end; p += 16) {
            int2 e = cv[p];
            s0 += __int_as_float(e.y) * v_in[e.x];
        }
        s0 += __shfl_xor(s0, 8, 16);
        s0 += __shfl_xor(s0, 4, 16);
        s0 += __shfl_xor(s0, 2, 16);
        s0 += __shfl_xor(s0, 1, 16);
        if (t == 0) {
            float sg = (s0 > 0.f) ? 1.f : ((s0 < 0.f) ? -1.f : 0.f);
            float w = s0 * scale - TAU * sg;
            v_out[row] = w;
            sq = w * w;
        }
    }
    for (int off = 32; off; off >>= 1) sq += __shfl_down(sq, off, 64);
    __shared__ float sh[4];
    int wv = threadIdx.x >> 6;
    if (lane == 0) sh[wv] = sq;
    __syncthreads();
    if (threadIdx.x == 0)
        atomicAdd(&norm_out[blockIdx.x & 63], sh[0] + sh[1] + sh[2] + sh[3]);
}

__global__ void finalize_kernel(const float* __restrict__ v,
                                const float* __restrict__ slots,
                                float* __restrict__ out, int n) {
    int lane = threadIdx.x & 63;
    float x = slots[lane];
#pragma unroll
    for (int off = 32; off; off >>= 1) x += __shfl_xor(x, off, 64);
    float inv = 1.f / fmaxf(sqrtf(x), 1e-12f);
    int i = blockIdx.x * 256 + threadIdx.x;
    if (i < n) out[i] = v[i] * inv;
}

extern "C" void kernel_launch(void* const* d_in, const int* in_sizes, int n_in,
                              void* d_out, int out_size, void* d_ws, size_t ws_size,
                              hipStream_t stream) {
    const int* A_row = (const int*)d_in[0];
    const int* A_col = (const int*)d_in[1];
    const float* A_val = (const float*)d_in[2];
    const int* L_row = (const int*)d_in[3];
    const int* L_col = (const int*)d_in[4];
    const float* L_val = (const float*)d_in[5];
    const float* embed = (const float*)d_in[6];
    const float* W1 = (const float*)d_in[7];
    const float* W2 = (const float*)d_in[8];
    const float* Ws = (const float*)d_in[9];
    float* out = (float*)d_out;

    const int E = in_sizes[0];
    const int D = 64;
    const int N = in_sizes[6] / D;
    const int ITERS = 10;
    const int NB = (N + BRW - 1) / BRW;   // buckets per matrix (1563)
    const int NB2 = 2 * NB;
    const int K = NB2 * 8;                // segment cursors

    char* ws = (char*)d_ws;
    size_t off = 0;
    auto carve = [&](size_t bytes) {
        void* p = ws + off;
        off += (bytes + 255) & ~(size_t)255;
        return p;
    };
    size_t feat_bytes = (size_t)N * D * sizeof(float);
    size_t tmp_bytes = (size_t)K * SSTRIDE * sizeof(int2);
    // X0/X1 and tmp share one region (tmp dead once place ran; X live after)
    char* base = (char*)carve(tmp_bytes > 2 * feat_bytes ? tmp_bytes : 2 * feat_bytes);
    float* X0 = (float*)base;
    float* X1 = (float*)(base + feat_bytes);
    int2* tmp = (int2*)base;
    int* A_rp = (int*)carve((size_t)(N + 1) * sizeof(int));
    int2* A_cv = (int2*)carve((size_t)E * sizeof(int2));
    int* L_rp = (int*)carve((size_t)(N + 1) * sizeof(int));
    int2* L_cv = (int2*)carve((size_t)E * sizeof(int2));
    int* cur = (int*)carve((size_t)K * sizeof(int));
    int* boff = (int*)carve((size_t)NB2 * sizeof(int));
    float* v_cur = (float*)carve((size_t)N * sizeof(float));
    float* v_new = (float*)carve((size_t)N * sizeof(float));
    float* norms = (float*)carve((size_t)ITERS * 64 * sizeof(float));

    int e_blocks = (E + 255) / 256;

    // ---- CSR build: XCD-local binned sort (per-matrix bin for L2 fit) ----
    init_kernel<<<(K + 255) / 256, 256, 0, stream>>>(cur, norms, K, ITERS * 64);
    bin_kernel<<<e_blocks, 256, 0, stream>>>(A_row, A_col, A_val, cur, tmp, E, 0);
    bin_kernel<<<e_blocks, 256, 0, stream>>>(L_row, L_col, L_val, cur, tmp, E, NB);
    scan_fused_kernel<<<1, 1024, 0, stream>>>(cur, boff, NB2);
    place_kernel<<<NB2, 256, 0, stream>>>(cur, boff, tmp,
                                          A_rp, L_rp, A_cv, L_cv, N, NB);

    // ---- two fused residual GNN layers (layer 2 also emits scores) ----
    int fl_blocks = 2048;
    fused_layer_kernel<<<fl_blocks, 256, 0, stream>>>(
        A_rp, A_cv, embed, W1, X0, nullptr, Ws, N);
    fused_layer_kernel<<<fl_blocks, 256, 0, stream>>>(
        A_rp, A_cv, X0, W2, X1, v_cur, Ws, N);

    // ---- power iterations (normalize folded; 64-slot norm partials) ----
    int p_blocks = (N * 16 + 255) / 256;
    int n_blocks = (N + 255) / 256;
    float* cur_v = v_cur;
    float* nxt_v = v_new;
    for (int it = 0; it < ITERS; ++it) {
        power_iter_kernel<<<p_blocks, 256, 0, stream>>>(
            L_rp, L_cv, cur_v, nxt_v,
            it ? (norms + (it - 1) * 64) : nullptr, norms + it * 64, N);
        float* t = cur_v; cur_v = nxt_v; nxt_v = t;
    }
    finalize_kernel<<<n_blocks, 256, 0, stream>>>(cur_v, norms + (ITERS - 1) * 64, out, N);
}

// Round 11
// 867.808 us; speedup vs baseline: 2.3004x; 1.0768x over previous
//
#include <hip/hip_runtime.h>
#include <hip/hip_bf16.h>
#include <math.h>

#define TAU 0.5f
#define BRW 64         // rows per bucket
#define SSTRIDE 256    // segment stride (entries): 2048 B, line-aligned
#define SCAP 254       // usable capacity (mean fill ~128, +11 sigma)

// ---------------------------------------------------------------------------
// CSR build v3: XCD-local binned sort, per-matrix bin pass (L2-footprint fit).
// ---------------------------------------------------------------------------
__global__ void init_kernel(int* __restrict__ cur, float* __restrict__ norms,
                            int K, int NN) {
    int k = blockIdx.x * 256 + threadIdx.x;
    if (k < K) cur[k] = k * SSTRIDE;
    if (k < NN) norms[k] = 0.f;
}

__global__ void bin_kernel(const int* __restrict__ row, const int* __restrict__ col,
                           const float* __restrict__ val,
                           int* __restrict__ cur, int2* __restrict__ tmp,
                           int E, int kbase) {
    // HW_REG_XCC_ID (id=20, offset 0, size 32): imm = (31<<11)|20 = 63508.
    int xcd = __builtin_amdgcn_s_getreg(63508) & 7;
    int e = blockIdx.x * 256 + threadIdx.x;
    if (e >= E) return;
    int r = row[e];
    int k = (kbase + (r >> 6)) * 8 + xcd;
    int p = atomicAdd(&cur[k], 1);
    if (p < k * SSTRIDE + SCAP)  // 11-sigma margin; clamp prevents OOB
        tmp[p] = make_int2(col[e] | ((r & 63) << 20), __float_as_int(val[e]));
}

// Single block: bucket totals from cursors + exclusive scan over NB2 buckets.
__global__ void scan_fused_kernel(const int* __restrict__ cur,
                                  int* __restrict__ boff, int NB2) {
    __shared__ int sh[1024];
    int t = threadIdx.x;  // 1024
    int b0 = t * 4;
    int v[4];
    int s = 0;
#pragma unroll
    for (int j = 0; j < 4; ++j) {
        int b = b0 + j;
        int c = 0;
        if (b < NB2) {
#pragma unroll
            for (int i = 0; i < 8; ++i) {
                int k = b * 8 + i;
                int f = cur[k] - k * SSTRIDE;
                c += min(max(f, 0), SCAP);
            }
        }
        v[j] = c;
        s += c;
    }
    sh[t] = s;
    __syncthreads();
    for (int off = 1; off < 1024; off <<= 1) {
        int x = (t >= off) ? sh[t - off] : 0;
        __syncthreads();
        sh[t] += x;
        __syncthreads();
    }
    int run = (t == 0) ? 0 : sh[t - 1];
#pragma unroll
    for (int j = 0; j < 4; ++j) {
        int b = b0 + j;
        if (b < NB2) boff[b] = run;
        run += v[j];
    }
}

// One block per bucket: LDS-sort bucket edges by row, emit row_ptr + cv.
__global__ void place_kernel(const int* __restrict__ cur,
                             const int* __restrict__ boff,
                             const int2* __restrict__ tmp,
                             int* __restrict__ rpA, int* __restrict__ rpL,
                             int2* __restrict__ cvA, int2* __restrict__ cvL,
                             int n, int NB) {
    int b = blockIdx.x;  // 0..2*NB-1
    int m = (b >= NB) ? 1 : 0;
    int lb = b - m * NB;
    int r0 = lb * BRW;
    int r1 = min(r0 + BRW, n);
    int* rp = m ? rpL : rpA;
    int2* cv = m ? cvL : cvA;
    int lbase = m ? boff[NB] : 0;           // L's cv/rp offsets are local
    int p0 = boff[b] - lbase;
    __shared__ int cnt[BRW], curs[BRW], rbase[BRW];
    __shared__ int fill[8], fbase[9];
    __shared__ int2 stage[8 * SCAP];        // 2032 int2 = 16.3 KB
    int t = threadIdx.x;
    if (t < BRW) cnt[t] = 0;
    if (t < 8) {
        int k = b * 8 + t;
        int f = cur[k] - k * SSTRIDE;
        fill[t] = min(max(f, 0), SCAP);
    }
    __syncthreads();
    if (t == 0) {
        int r = 0;
#pragma unroll
        for (int i = 0; i < 8; ++i) { fbase[i] = r; r += fill[i]; }
        fbase[8] = r;
    }
    __syncthreads();
    int total = fbase[8];
    // coalesced per-segment load into stage + LDS row histogram
#pragma unroll
    for (int sg = 0; sg < 8; ++sg) {
        int f = fill[sg];
        const int2* src = tmp + (size_t)(b * 8 + sg) * SSTRIDE;
        int fb = fbase[sg];
        for (int i = t; i < f; i += 256) {
            int2 e = src[i];
            stage[fb + i] = e;
            atomicAdd(&cnt[(e.x >> 20) & 63], 1);
        }
    }
    __syncthreads();
    // exclusive scan over 64 row counts (wave 0, shfl ladder)
    if (t < 64) {
        int c = cnt[t];
        int sc = c;
#pragma unroll
        for (int off = 1; off < 64; off <<= 1) {
            int y = __shfl_up(sc, off, 64);
            if (t >= off) sc += y;
        }
        rbase[t] = sc - c;
        curs[t] = sc - c;
    }
    __syncthreads();
    if (t < r1 - r0) rp[r0 + t] = p0 + rbase[t];
    if (t == 0 && lb == NB - 1) rp[n] = p0 + total;  // sentinel
    __syncthreads();
    for (int i = t; i < total; i += 256) {
        int2 e = stage[i];
        int pos = atomicAdd(&curs[(e.x >> 20) & 63], 1);
        cv[p0 + pos] = make_int2(e.x & 0xFFFFF, e.y);
    }
}

// ---------------------------------------------------------------------------
// Fused GNN layer v3: one wave per ROW PAIR (rows 2r, 2r+1), half-wave float2.
//   Pair edges are contiguous in CSR: one unified gather loop over
//   [rp[2r], rp[2r+2]) keeps 8 loads in flight spanning both rows; edge
//   routed to accA/accB by p < rp[2r+1] predication. The two matvecs share
//   LDS W reads (32 b64/pair vs 64).
// ---------------------------------------------------------------------------
__global__ void fused_layer_kernel(const int* __restrict__ row_ptr,
                                   const int2* __restrict__ cv,
                                   const float* __restrict__ X,
                                   const float* __restrict__ W,
                                   float* __restrict__ Xn,
                                   float* __restrict__ s,
                                   const float* __restrict__ Wsv, int n) {
    __shared__ float Wt[64 * 66];       // Wt[k*66 + f] = W[f][k]; even stride
    int tid = threadIdx.x;
    for (int i = tid; i < 4096; i += 256) {
        int j = i >> 6, k = i & 63;     // W[j,k] row-major
        Wt[k * 66 + j] = W[i];
    }
    __syncthreads();
    int lane = tid & 63;
    int sl = lane & 31;
    int half = lane >> 5;
    int wv = tid >> 6;
    float ws0 = 0.f, ws1 = 0.f;
    if (s != nullptr) { ws0 = Wsv[2 * sl]; ws1 = Wsv[2 * sl + 1]; }
    int stride = gridDim.x * 8;          // rows per sweep (4 waves * 2 rows)
    for (int row = (blockIdx.x * 4 + wv) * 2; row < n; row += stride) {
        int rB = row + 1;
        int p0 = row_ptr[row];
        int mb = row_ptr[rB];                        // A/B boundary
        int end = (rB < n) ? row_ptr[rB + 1] : mb;
        float2 aA0 = {0.f, 0.f}, aA1 = {0.f, 0.f};
        float2 aB0 = {0.f, 0.f}, aB1 = {0.f, 0.f};
        int p = p0 + half;
        for (; p + 6 < end; p += 8) {
            int2 e0 = cv[p], e1 = cv[p + 2], e2 = cv[p + 4], e3 = cv[p + 6];
            float2 x0 = *(const float2*)&X[(size_t)e0.x * 64 + 2 * sl];
            float2 x1 = *(const float2*)&X[(size_t)e1.x * 64 + 2 * sl];
            float2 x2 = *(const float2*)&X[(size_t)e2.x * 64 + 2 * sl];
            float2 x3 = *(const float2*)&X[(size_t)e3.x * 64 + 2 * sl];
            float v0 = __int_as_float(e0.y), v1 = __int_as_float(e1.y);
            float v2 = __int_as_float(e2.y), v3 = __int_as_float(e3.y);
            float f0 = (p < mb) ? v0 : 0.f;      float g0 = v0 - f0;
            float f1 = (p + 2 < mb) ? v1 : 0.f;  float g1 = v1 - f1;
            float f2 = (p + 4 < mb) ? v2 : 0.f;  float g2 = v2 - f2;
            float f3 = (p + 6 < mb) ? v3 : 0.f;  float g3 = v3 - f3;
            aA0.x += f0 * x0.x; aA0.y += f0 * x0.y;
            aB0.x += g0 * x0.x; aB0.y += g0 * x0.y;
            aA1.x += f1 * x1.x; aA1.y += f1 * x1.y;
            aB1.x += g1 * x1.x; aB1.y += g1 * x1.y;
            aA0.x += f2 * x2.x; aA0.y += f2 * x2.y;
            aB0.x += g2 * x2.x; aB0.y += g2 * x2.y;
            aA1.x += f3 * x3.x; aA1.y += f3 * x3.y;
            aB1.x += g3 * x3.x; aB1.y += g3 * x3.y;
        }
        for (; p < end; p += 2) {
            int2 e = cv[p];
            float2 x = *(const float2*)&X[(size_t)e.x * 64 + 2 * sl];
            float v = __int_as_float(e.y);
            float f = (p < mb) ? v : 0.f;
            float g = v - f;
            aA0.x += f * x.x; aA0.y += f * x.y;
            aB0.x += g * x.x; aB0.y += g * x.y;
        }
        float2 accA, accB;
        accA.x = aA0.x + aA1.x; accA.y = aA0.y + aA1.y;
        accB.x = aB0.x + aB1.x; accB.y = aB0.y + aB1.y;
        accA.x += __shfl_xor(accA.x, 32, 64);
        accA.y += __shfl_xor(accA.y, 32, 64);
        accB.x += __shfl_xor(accB.x, 32, 64);
        accB.y += __shfl_xor(accB.y, 32, 64);
        // ---- shared matvec: half h covers k in [32h, 32h+32) ----
        float hxA = 0.f, hyA = 0.f, hxB = 0.f, hyB = 0.f;
        int kbase = 32 * half;
#pragma unroll
        for (int kk = 0; kk < 32; kk += 2) {
            int k = kbase + kk;
            float axA = __shfl(accA.x, k >> 1, 64);
            float ayA = __shfl(accA.y, k >> 1, 64);
            float axB = __shfl(accB.x, k >> 1, 64);
            float ayB = __shfl(accB.y, k >> 1, 64);
            float2 w0 = *(const float2*)&Wt[k * 66 + 2 * sl];
            float2 w1 = *(const float2*)&Wt[(k + 1) * 66 + 2 * sl];
            hxA += axA * w0.x + ayA * w1.x;
            hyA += axA * w0.y + ayA * w1.y;
            hxB += axB * w0.x + ayB * w1.x;
            hyB += axB * w0.y + ayB * w1.y;
        }
        hxA += __shfl_xor(hxA, 32, 64);
        hyA += __shfl_xor(hyA, 32, 64);
        hxB += __shfl_xor(hxB, 32, 64);
        hyB += __shfl_xor(hyB, 32, 64);
        // ---- residual + store + folded score, row A ----
        float2 xvA = *(const float2*)&X[(size_t)row * 64 + 2 * sl];
        float2 oA;
        oA.x = xvA.x + fmaxf(hxA, 0.f);
        oA.y = xvA.y + fmaxf(hyA, 0.f);
        if (half == 0) *(float2*)&Xn[(size_t)row * 64 + 2 * sl] = oA;
        if (s != nullptr) {
            float d = oA.x * ws0 + oA.y * ws1;
#pragma unroll
            for (int off = 16; off; off >>= 1) d += __shfl_down(d, off, 32);
            if (lane == 0) s[row] = d;
        }
        // ---- row B ----
        if (rB < n) {
            float2 xvB = *(const float2*)&X[(size_t)rB * 64 + 2 * sl];
            float2 oB;
            oB.x = xvB.x + fmaxf(hxB, 0.f);
            oB.y = xvB.y + fmaxf(hyB, 0.f);
            if (half == 0) *(float2*)&Xn[(size_t)rB * 64 + 2 * sl] = oB;
            if (s != nullptr) {
                float d = oB.x * ws0 + oB.y * ws1;
#pragma unroll
                for (int off = 16; off; off >>= 1) d += __shfl_down(d, off, 32);
                if (lane == 0) s[rB] = d;
            }
        }
    }
}

// ---------------------------------------------------------------------------
// Fused power iteration v3: 4 lanes per row, 4-deep independent load chains
// (was 1 cv load + 1 dependent gather in flight per lane -> now 4+4).
// Per-iteration launch (coop grid.sync measured ~134us/iter -> never).
// ---------------------------------------------------------------------------
__global__ void power_iter_kernel(const int* __restrict__ row_ptr,
                                  const int2* __restrict__ cv,
                                  const float* __restrict__ v_in,
                                  float* __restrict__ v_out,
                                  const float* __restrict__ norm_prev,  // 64 slots or null
                                  float* __restrict__ norm_out,         // 64 slots
                                  int n) {
    int lane = threadIdx.x & 63;
    float scale = 1.f;
    if (norm_prev) {
        float x = norm_prev[lane];
#pragma unroll
        for (int off = 32; off; off >>= 1) x += __shfl_xor(x, off, 64);
        scale = 1.f / fmaxf(sqrtf(x), 1e-12f);
    }
    int g = blockIdx.x * 256 + threadIdx.x;
    int row = g >> 2;
    int t = g & 3;
    float sq = 0.f;
    if (row < n) {
        int p = row_ptr[row] + t;
        int end = row_ptr[row + 1];
        float s0 = 0.f, s1 = 0.f, s2 = 0.f, s3 = 0.f;
        for (; p + 12 < end; p += 16) {
            int2 e0 = cv[p], e1 = cv[p + 4], e2 = cv[p + 8], e3 = cv[p + 12];
            s0 += __int_as_float(e0.y) * v_in[e0.x];
            s1 += __int_as_float(e1.y) * v_in[e1.x];
            s2 += __int_as_float(e2.y) * v_in[e2.x];
            s3 += __int_as_float(e3.y) * v_in[e3.x];
        }
        for (; p < end; p += 4) {
            int2 e = cv[p];
            s0 += __int_as_float(e.y) * v_in[e.x];
        }
        float sv = (s0 + s1) + (s2 + s3);
        sv += __shfl_xor(sv, 2, 4);
        sv += __shfl_xor(sv, 1, 4);
        if (t == 0) {
            float sg = (sv > 0.f) ? 1.f : ((sv < 0.f) ? -1.f : 0.f);
            float w = sv * scale - TAU * sg;
            v_out[row] = w;
            sq = w * w;
        }
    }
    for (int off = 32; off; off >>= 1) sq += __shfl_down(sq, off, 64);
    __shared__ float sh[4];
    int wv = threadIdx.x >> 6;
    if (lane == 0) sh[wv] = sq;
    __syncthreads();
    if (threadIdx.x == 0)
        atomicAdd(&norm_out[blockIdx.x & 63], sh[0] + sh[1] + sh[2] + sh[3]);
}

__global__ void finalize_kernel(const float* __restrict__ v,
                                const float* __restrict__ slots,
                                float* __restrict__ out, int n) {
    int lane = threadIdx.x & 63;
    float x = slots[lane];
#pragma unroll
    for (int off = 32; off; off >>= 1) x += __shfl_xor(x, off, 64);
    float inv = 1.f / fmaxf(sqrtf(x), 1e-12f);
    int i = blockIdx.x * 256 + threadIdx.x;
    if (i < n) out[i] = v[i] * inv;
}

extern "C" void kernel_launch(void* const* d_in, const int* in_sizes, int n_in,
                              void* d_out, int out_size, void* d_ws, size_t ws_size,
                              hipStream_t stream) {
    const int* A_row = (const int*)d_in[0];
    const int* A_col = (const int*)d_in[1];
    const float* A_val = (const float*)d_in[2];
    const int* L_row = (const int*)d_in[3];
    const int* L_col = (const int*)d_in[4];
    const float* L_val = (const float*)d_in[5];
    const float* embed = (const float*)d_in[6];
    const float* W1 = (const float*)d_in[7];
    const float* W2 = (const float*)d_in[8];
    const float* Ws = (const float*)d_in[9];
    float* out = (float*)d_out;

    const int E = in_sizes[0];
    const int D = 64;
    const int N = in_sizes[6] / D;
    const int ITERS = 10;
    const int NB = (N + BRW - 1) / BRW;   // buckets per matrix (1563)
    const int NB2 = 2 * NB;
    const int K = NB2 * 8;                // segment cursors

    char* ws = (char*)d_ws;
    size_t off = 0;
    auto carve = [&](size_t bytes) {
        void* p = ws + off;
        off += (bytes + 255) & ~(size_t)255;
        return p;
    };
    size_t feat_bytes = (size_t)N * D * sizeof(float);
    size_t tmp_bytes = (size_t)K * SSTRIDE * sizeof(int2);
    // X0/X1 and tmp share one region (tmp dead once place ran; X live after)
    char* base = (char*)carve(tmp_bytes > 2 * feat_bytes ? tmp_bytes : 2 * feat_bytes);
    float* X0 = (float*)base;
    float* X1 = (float*)(base + feat_bytes);
    int2* tmp = (int2*)base;
    int* A_rp = (int*)carve((size_t)(N + 1) * sizeof(int));
    int2* A_cv = (int2*)carve((size_t)E * sizeof(int2));
    int* L_rp = (int*)carve((size_t)(N + 1) * sizeof(int));
    int2* L_cv = (int2*)carve((size_t)E * sizeof(int2));
    int* cur = (int*)carve((size_t)K * sizeof(int));
    int* boff = (int*)carve((size_t)NB2 * sizeof(int));
    float* v_cur = (float*)carve((size_t)N * sizeof(float));
    float* v_new = (float*)carve((size_t)N * sizeof(float));
    float* norms = (float*)carve((size_t)ITERS * 64 * sizeof(float));

    int e_blocks = (E + 255) / 256;

    // ---- CSR build: XCD-local binned sort (per-matrix bin for L2 fit) ----
    init_kernel<<<(K + 255) / 256, 256, 0, stream>>>(cur, norms, K, ITERS * 64);
    bin_kernel<<<e_blocks, 256, 0, stream>>>(A_row, A_col, A_val, cur, tmp, E, 0);
    bin_kernel<<<e_blocks, 256, 0, stream>>>(L_row, L_col, L_val, cur, tmp, E, NB);
    scan_fused_kernel<<<1, 1024, 0, stream>>>(cur, boff, NB2);
    place_kernel<<<NB2, 256, 0, stream>>>(cur, boff, tmp,
                                          A_rp, L_rp, A_cv, L_cv, N, NB);

    // ---- two fused residual GNN layers (layer 2 also emits scores) ----
    int fl_blocks = 2048;
    fused_layer_kernel<<<fl_blocks, 256, 0, stream>>>(
        A_rp, A_cv, embed, W1, X0, nullptr, Ws, N);
    fused_layer_kernel<<<fl_blocks, 256, 0, stream>>>(
        A_rp, A_cv, X0, W2, X1, v_cur, Ws, N);

    // ---- power iterations (normalize folded; 64-slot norm partials) ----
    int p_blocks = (N * 4 + 255) / 256;
    int n_blocks = (N + 255) / 256;
    float* cur_v = v_cur;
    float* nxt_v = v_new;
    for (int it = 0; it < ITERS; ++it) {
        power_iter_kernel<<<p_blocks, 256, 0, stream>>>(
            L_rp, L_cv, cur_v, nxt_v,
            it ? (norms + (it - 1) * 64) : nullptr, norms + it * 64, N);
        float* t = cur_v; cur_v = nxt_v; nxt_v = t;
    }
    finalize_kernel<<<n_blocks, 256, 0, stream>>>(cur_v, norms + (ITERS - 1) * 64, out, N);
}

// Round 12
// 694.111 us; speedup vs baseline: 2.8760x; 1.2502x over previous
//
#include <hip/hip_runtime.h>
#include <hip/hip_bf16.h>
#include <math.h>

#define TAU 0.5f
#define BRW 64         // rows per bucket
#define SSTRIDE 256    // segment stride (entries): 2048 B, line-aligned
#define SCAP 254       // usable capacity (mean fill ~128, +11 sigma)

// ---------------------------------------------------------------------------
// CSR build v3: XCD-local binned sort, per-matrix bin pass (L2-footprint fit).
// ---------------------------------------------------------------------------
__global__ void init_kernel(int* __restrict__ cur, float* __restrict__ norms,
                            int K, int NN) {
    int k = blockIdx.x * 256 + threadIdx.x;
    if (k < K) cur[k] = k * SSTRIDE;
    if (k < NN) norms[k] = 0.f;
}

__global__ void bin_kernel(const int* __restrict__ row, const int* __restrict__ col,
                           const float* __restrict__ val,
                           int* __restrict__ cur, int2* __restrict__ tmp,
                           int E, int kbase) {
    // HW_REG_XCC_ID (id=20, offset 0, size 32): imm = (31<<11)|20 = 63508.
    int xcd = __builtin_amdgcn_s_getreg(63508) & 7;
    int e = blockIdx.x * 256 + threadIdx.x;
    if (e >= E) return;
    int r = row[e];
    int k = (kbase + (r >> 6)) * 8 + xcd;
    int p = atomicAdd(&cur[k], 1);
    if (p < k * SSTRIDE + SCAP)  // 11-sigma margin; clamp prevents OOB
        tmp[p] = make_int2(col[e] | ((r & 63) << 20), __float_as_int(val[e]));
}

// Single block: bucket totals from cursors + exclusive scan over NB2 buckets.
__global__ void scan_fused_kernel(const int* __restrict__ cur,
                                  int* __restrict__ boff, int NB2) {
    __shared__ int sh[1024];
    int t = threadIdx.x;  // 1024
    int b0 = t * 4;
    int v[4];
    int s = 0;
#pragma unroll
    for (int j = 0; j < 4; ++j) {
        int b = b0 + j;
        int c = 0;
        if (b < NB2) {
#pragma unroll
            for (int i = 0; i < 8; ++i) {
                int k = b * 8 + i;
                int f = cur[k] - k * SSTRIDE;
                c += min(max(f, 0), SCAP);
            }
        }
        v[j] = c;
        s += c;
    }
    sh[t] = s;
    __syncthreads();
    for (int off = 1; off < 1024; off <<= 1) {
        int x = (t >= off) ? sh[t - off] : 0;
        __syncthreads();
        sh[t] += x;
        __syncthreads();
    }
    int run = (t == 0) ? 0 : sh[t - 1];
#pragma unroll
    for (int j = 0; j < 4; ++j) {
        int b = b0 + j;
        if (b < NB2) boff[b] = run;
        run += v[j];
    }
}

// One block per bucket: LDS-sort bucket edges by row, emit row_ptr + cv.
__global__ void place_kernel(const int* __restrict__ cur,
                             const int* __restrict__ boff,
                             const int2* __restrict__ tmp,
                             int* __restrict__ rpA, int* __restrict__ rpL,
                             int2* __restrict__ cvA, int2* __restrict__ cvL,
                             int n, int NB) {
    int b = blockIdx.x;  // 0..2*NB-1
    int m = (b >= NB) ? 1 : 0;
    int lb = b - m * NB;
    int r0 = lb * BRW;
    int r1 = min(r0 + BRW, n);
    int* rp = m ? rpL : rpA;
    int2* cv = m ? cvL : cvA;
    int lbase = m ? boff[NB] : 0;           // L's cv/rp offsets are local
    int p0 = boff[b] - lbase;
    __shared__ int cnt[BRW], curs[BRW], rbase[BRW];
    __shared__ int fill[8], fbase[9];
    __shared__ int2 stage[8 * SCAP];        // 2032 int2 = 16.3 KB
    int t = threadIdx.x;
    if (t < BRW) cnt[t] = 0;
    if (t < 8) {
        int k = b * 8 + t;
        int f = cur[k] - k * SSTRIDE;
        fill[t] = min(max(f, 0), SCAP);
    }
    __syncthreads();
    if (t == 0) {
        int r = 0;
#pragma unroll
        for (int i = 0; i < 8; ++i) { fbase[i] = r; r += fill[i]; }
        fbase[8] = r;
    }
    __syncthreads();
    int total = fbase[8];
    // coalesced per-segment load into stage + LDS row histogram
#pragma unroll
    for (int sg = 0; sg < 8; ++sg) {
        int f = fill[sg];
        const int2* src = tmp + (size_t)(b * 8 + sg) * SSTRIDE;
        int fb = fbase[sg];
        for (int i = t; i < f; i += 256) {
            int2 e = src[i];
            stage[fb + i] = e;
            atomicAdd(&cnt[(e.x >> 20) & 63], 1);
        }
    }
    __syncthreads();
    // exclusive scan over 64 row counts (wave 0, shfl ladder)
    if (t < 64) {
        int c = cnt[t];
        int sc = c;
#pragma unroll
        for (int off = 1; off < 64; off <<= 1) {
            int y = __shfl_up(sc, off, 64);
            if (t >= off) sc += y;
        }
        rbase[t] = sc - c;
        curs[t] = sc - c;
    }
    __syncthreads();
    if (t < r1 - r0) rp[r0 + t] = p0 + rbase[t];
    if (t == 0 && lb == NB - 1) rp[n] = p0 + total;  // sentinel
    __syncthreads();
    for (int i = t; i < total; i += 256) {
        int2 e = stage[i];
        int pos = atomicAdd(&curs[(e.x >> 20) & 63], 1);
        cv[p0 + pos] = make_int2(e.x & 0xFFFFF, e.y);
    }
}

// ---------------------------------------------------------------------------
// Fused GNN layer v2 (reverted from v3 row-pairing: R11 profile showed
// FETCH 192->474 MB, dur 114->218 us for v3 — pair working set thrashed L2).
// One wave per row, half-wave float2 layout:
//   lane = 32*half + sl; lane owns features {2sl, 2sl+1} (float2).
//   Half h processes edges p0+h, p0+h+2, ... -> one VMEM instr fetches TWO
//   edge rows (512 B/wave). Matvec: k-range split by half, float2 broadcasts.
// ---------------------------------------------------------------------------
__global__ void fused_layer_kernel(const int* __restrict__ row_ptr,
                                   const int2* __restrict__ cv,
                                   const float* __restrict__ X,
                                   const float* __restrict__ W,
                                   float* __restrict__ Xn,
                                   float* __restrict__ s,
                                   const float* __restrict__ Wsv, int n) {
    __shared__ float Wt[64 * 66];       // Wt[k*66 + f] = W[f][k]; even stride
    int tid = threadIdx.x;
    for (int i = tid; i < 4096; i += 256) {
        int j = i >> 6, k = i & 63;     // W[j,k] row-major
        Wt[k * 66 + j] = W[i];
    }
    __syncthreads();
    int lane = tid & 63;
    int sl = lane & 31;
    int half = lane >> 5;
    int wv = tid >> 6;
    float ws0 = 0.f, ws1 = 0.f;
    if (s != nullptr) { ws0 = Wsv[2 * sl]; ws1 = Wsv[2 * sl + 1]; }
    int nwaves = gridDim.x * 4;
    for (int row = blockIdx.x * 4 + wv; row < n; row += nwaves) {
        int p0 = row_ptr[row];
        int end = row_ptr[row + 1];
        // ---- gather: half-split edge streams, 4 pairs unrolled ----
        float2 a0 = {0.f, 0.f}, a1 = {0.f, 0.f}, a2 = {0.f, 0.f}, a3 = {0.f, 0.f};
        int p = p0 + half;
        for (; p + 6 < end; p += 8) {
            int2 e0 = cv[p], e1 = cv[p + 2], e2 = cv[p + 4], e3 = cv[p + 6];
            float2 x0 = *(const float2*)&X[(size_t)e0.x * 64 + 2 * sl];
            float2 x1 = *(const float2*)&X[(size_t)e1.x * 64 + 2 * sl];
            float2 x2 = *(const float2*)&X[(size_t)e2.x * 64 + 2 * sl];
            float2 x3 = *(const float2*)&X[(size_t)e3.x * 64 + 2 * sl];
            float v0 = __int_as_float(e0.y), v1 = __int_as_float(e1.y);
            float v2 = __int_as_float(e2.y), v3 = __int_as_float(e3.y);
            a0.x += v0 * x0.x; a0.y += v0 * x0.y;
            a1.x += v1 * x1.x; a1.y += v1 * x1.y;
            a2.x += v2 * x2.x; a2.y += v2 * x2.y;
            a3.x += v3 * x3.x; a3.y += v3 * x3.y;
        }
        for (; p < end; p += 2) {
            int2 e = cv[p];
            float2 x = *(const float2*)&X[(size_t)e.x * 64 + 2 * sl];
            float v = __int_as_float(e.y);
            a0.x += v * x.x; a0.y += v * x.y;
        }
        float2 acc;
        acc.x = (a0.x + a1.x) + (a2.x + a3.x);
        acc.y = (a0.y + a1.y) + (a2.y + a3.y);
        // combine halves: both halves then hold full AX features {2sl,2sl+1}
        acc.x += __shfl_xor(acc.x, 32, 64);
        acc.y += __shfl_xor(acc.y, 32, 64);
        // ---- matvec: half h covers k in [32h, 32h+32) ----
        float hx = 0.f, hy = 0.f;
        int kbase = 32 * half;
#pragma unroll
        for (int kk = 0; kk < 32; kk += 2) {
            int k = kbase + kk;
            float ax = __shfl(acc.x, k >> 1, 64);  // acc[k]   (k even)
            float ay = __shfl(acc.y, k >> 1, 64);  // acc[k+1]
            float2 w0 = *(const float2*)&Wt[k * 66 + 2 * sl];
            float2 w1 = *(const float2*)&Wt[(k + 1) * 66 + 2 * sl];
            hx += ax * w0.x + ay * w1.x;
            hy += ax * w0.y + ay * w1.y;
        }
        hx += __shfl_xor(hx, 32, 64);
        hy += __shfl_xor(hy, 32, 64);
        // ---- residual + store (half 0 writes) + folded score ----
        float2 xv = *(const float2*)&X[(size_t)row * 64 + 2 * sl];
        float2 o;
        o.x = xv.x + fmaxf(hx, 0.f);
        o.y = xv.y + fmaxf(hy, 0.f);
        if (half == 0) *(float2*)&Xn[(size_t)row * 64 + 2 * sl] = o;
        if (s != nullptr) {
            float d = o.x * ws0 + o.y * ws1;
#pragma unroll
            for (int off = 16; off; off >>= 1) d += __shfl_down(d, off, 32);
            if (lane == 0) s[row] = d;
        }
    }
}

// ---------------------------------------------------------------------------
// Fused power iteration v3: 4 lanes per row, 4-deep independent load chains.
// Per-iteration launch (coop grid.sync measured ~134us/iter -> never).
// ---------------------------------------------------------------------------
__global__ void power_iter_kernel(const int* __restrict__ row_ptr,
                                  const int2* __restrict__ cv,
                                  const float* __restrict__ v_in,
                                  float* __restrict__ v_out,
                                  const float* __restrict__ norm_prev,  // 64 slots or null
                                  float* __restrict__ norm_out,         // 64 slots
                                  int n) {
    int lane = threadIdx.x & 63;
    float scale = 1.f;
    if (norm_prev) {
        float x = norm_prev[lane];
#pragma unroll
        for (int off = 32; off; off >>= 1) x += __shfl_xor(x, off, 64);
        scale = 1.f / fmaxf(sqrtf(x), 1e-12f);
    }
    int g = blockIdx.x * 256 + threadIdx.x;
    int row = g >> 2;
    int t = g & 3;
    float sq = 0.f;
    if (row < n) {
        int p = row_ptr[row] + t;
        int end = row_ptr[row + 1];
        float s0 = 0.f, s1 = 0.f, s2 = 0.f, s3 = 0.f;
        for (; p + 12 < end; p += 16) {
            int2 e0 = cv[p], e1 = cv[p + 4], e2 = cv[p + 8], e3 = cv[p + 12];
            s0 += __int_as_float(e0.y) * v_in[e0.x];
            s1 += __int_as_float(e1.y) * v_in[e1.x];
            s2 += __int_as_float(e2.y) * v_in[e2.x];
            s3 += __int_as_float(e3.y) * v_in[e3.x];
        }
        for (; p < end; p += 4) {
            int2 e = cv[p];
            s0 += __int_as_float(e.y) * v_in[e.x];
        }
        float sv = (s0 + s1) + (s2 + s3);
        sv += __shfl_xor(sv, 2, 4);
        sv += __shfl_xor(sv, 1, 4);
        if (t == 0) {
            float sg = (sv > 0.f) ? 1.f : ((sv < 0.f) ? -1.f : 0.f);
            float w = sv * scale - TAU * sg;
            v_out[row] = w;
            sq = w * w;
        }
    }
    for (int off = 32; off; off >>= 1) sq += __shfl_down(sq, off, 64);
    __shared__ float sh[4];
    int wv = threadIdx.x >> 6;
    if (lane == 0) sh[wv] = sq;
    __syncthreads();
    if (threadIdx.x == 0)
        atomicAdd(&norm_out[blockIdx.x & 63], sh[0] + sh[1] + sh[2] + sh[3]);
}

__global__ void finalize_kernel(const float* __restrict__ v,
                                const float* __restrict__ slots,
                                float* __restrict__ out, int n) {
    int lane = threadIdx.x & 63;
    float x = slots[lane];
#pragma unroll
    for (int off = 32; off; off >>= 1) x += __shfl_xor(x, off, 64);
    float inv = 1.f / fmaxf(sqrtf(x), 1e-12f);
    int i = blockIdx.x * 256 + threadIdx.x;
    if (i < n) out[i] = v[i] * inv;
}

extern "C" void kernel_launch(void* const* d_in, const int* in_sizes, int n_in,
                              void* d_out, int out_size, void* d_ws, size_t ws_size,
                              hipStream_t stream) {
    const int* A_row = (const int*)d_in[0];
    const int* A_col = (const int*)d_in[1];
    const float* A_val = (const float*)d_in[2];
    const int* L_row = (const int*)d_in[3];
    const int* L_col = (const int*)d_in[4];
    const float* L_val = (const float*)d_in[5];
    const float* embed = (const float*)d_in[6];
    const float* W1 = (const float*)d_in[7];
    const float* W2 = (const float*)d_in[8];
    const float* Ws = (const float*)d_in[9];
    float* out = (float*)d_out;

    const int E = in_sizes[0];
    const int D = 64;
    const int N = in_sizes[6] / D;
    const int ITERS = 10;
    const int NB = (N + BRW - 1) / BRW;   // buckets per matrix (1563)
    const int NB2 = 2 * NB;
    const int K = NB2 * 8;                // segment cursors

    char* ws = (char*)d_ws;
    size_t off = 0;
    auto carve = [&](size_t bytes) {
        void* p = ws + off;
        off += (bytes + 255) & ~(size_t)255;
        return p;
    };
    size_t feat_bytes = (size_t)N * D * sizeof(float);
    size_t tmp_bytes = (size_t)K * SSTRIDE * sizeof(int2);
    // X0/X1 and tmp share one region (tmp dead once place ran; X live after)
    char* base = (char*)carve(tmp_bytes > 2 * feat_bytes ? tmp_bytes : 2 * feat_bytes);
    float* X0 = (float*)base;
    float* X1 = (float*)(base + feat_bytes);
    int2* tmp = (int2*)base;
    int* A_rp = (int*)carve((size_t)(N + 1) * sizeof(int));
    int2* A_cv = (int2*)carve((size_t)E * sizeof(int2));
    int* L_rp = (int*)carve((size_t)(N + 1) * sizeof(int));
    int2* L_cv = (int2*)carve((size_t)E * sizeof(int2));
    int* cur = (int*)carve((size_t)K * sizeof(int));
    int* boff = (int*)carve((size_t)NB2 * sizeof(int));
    float* v_cur = (float*)carve((size_t)N * sizeof(float));
    float* v_new = (float*)carve((size_t)N * sizeof(float));
    float* norms = (float*)carve((size_t)ITERS * 64 * sizeof(float));

    int e_blocks = (E + 255) / 256;

    // ---- CSR build: XCD-local binned sort (per-matrix bin for L2 fit) ----
    init_kernel<<<(K + 255) / 256, 256, 0, stream>>>(cur, norms, K, ITERS * 64);
    bin_kernel<<<e_blocks, 256, 0, stream>>>(A_row, A_col, A_val, cur, tmp, E, 0);
    bin_kernel<<<e_blocks, 256, 0, stream>>>(L_row, L_col, L_val, cur, tmp, E, NB);
    scan_fused_kernel<<<1, 1024, 0, stream>>>(cur, boff, NB2);
    place_kernel<<<NB2, 256, 0, stream>>>(cur, boff, tmp,
                                          A_rp, L_rp, A_cv, L_cv, N, NB);

    // ---- two fused residual GNN layers (layer 2 also emits scores) ----
    int fl_blocks = 2048;
    fused_layer_kernel<<<fl_blocks, 256, 0, stream>>>(
        A_rp, A_cv, embed, W1, X0, nullptr, Ws, N);
    fused_layer_kernel<<<fl_blocks, 256, 0, stream>>>(
        A_rp, A_cv, X0, W2, X1, v_cur, Ws, N);

    // ---- power iterations (normalize folded; 64-slot norm partials) ----
    int p_blocks = (N * 4 + 255) / 256;
    int n_blocks = (N + 255) / 256;
    float* cur_v = v_cur;
    float* nxt_v = v_new;
    for (int it = 0; it < ITERS; ++it) {
        power_iter_kernel<<<p_blocks, 256, 0, stream>>>(
            L_rp, L_cv, cur_v, nxt_v,
            it ? (norms + (it - 1) * 64) : nullptr, norms + it * 64, N);
        float* t = cur_v; cur_v = nxt_v; nxt_v = t;
    }
    finalize_kernel<<<n_blocks, 256, 0, stream>>>(cur_v, norms + (ITERS - 1) * 64, out, N);
}

// Round 13
// 678.227 us; speedup vs baseline: 2.9434x; 1.0234x over previous
//
#include <hip/hip_runtime.h>
#include <hip/hip_bf16.h>
#include <math.h>

#define TAU 0.5f
#define BRW 64         // rows per bucket
#define SSTRIDE 256    // segment stride (entries): 2048 B, line-aligned
#define SCAP 254       // usable capacity (mean fill ~128, +11 sigma)

// ---------------------------------------------------------------------------
// CSR build v3: XCD-local binned sort, per-matrix bin pass (L2-footprint fit).
// ---------------------------------------------------------------------------
__global__ void init_kernel(int* __restrict__ cur, float* __restrict__ norms,
                            int K, int NN) {
    int k = blockIdx.x * 256 + threadIdx.x;
    if (k < K) cur[k] = k * SSTRIDE;
    if (k < NN) norms[k] = 0.f;
}

__global__ void bin_kernel(const int* __restrict__ row, const int* __restrict__ col,
                           const float* __restrict__ val,
                           int* __restrict__ cur, int2* __restrict__ tmp,
                           int E, int kbase) {
    // HW_REG_XCC_ID (id=20, offset 0, size 32): imm = (31<<11)|20 = 63508.
    int xcd = __builtin_amdgcn_s_getreg(63508) & 7;
    int e = blockIdx.x * 256 + threadIdx.x;
    if (e >= E) return;
    int r = row[e];
    int k = (kbase + (r >> 6)) * 8 + xcd;
    int p = atomicAdd(&cur[k], 1);
    if (p < k * SSTRIDE + SCAP)  // 11-sigma margin; clamp prevents OOB
        tmp[p] = make_int2(col[e] | ((r & 63) << 20), __float_as_int(val[e]));
}

// Single block: bucket totals from cursors + exclusive scan over NB2 buckets.
__global__ void scan_fused_kernel(const int* __restrict__ cur,
                                  int* __restrict__ boff, int NB2) {
    __shared__ int sh[1024];
    int t = threadIdx.x;  // 1024
    int b0 = t * 4;
    int v[4];
    int s = 0;
#pragma unroll
    for (int j = 0; j < 4; ++j) {
        int b = b0 + j;
        int c = 0;
        if (b < NB2) {
#pragma unroll
            for (int i = 0; i < 8; ++i) {
                int k = b * 8 + i;
                int f = cur[k] - k * SSTRIDE;
                c += min(max(f, 0), SCAP);
            }
        }
        v[j] = c;
        s += c;
    }
    sh[t] = s;
    __syncthreads();
    for (int off = 1; off < 1024; off <<= 1) {
        int x = (t >= off) ? sh[t - off] : 0;
        __syncthreads();
        sh[t] += x;
        __syncthreads();
    }
    int run = (t == 0) ? 0 : sh[t - 1];
#pragma unroll
    for (int j = 0; j < 4; ++j) {
        int b = b0 + j;
        if (b < NB2) boff[b] = run;
        run += v[j];
    }
}

// One block per bucket: LDS-sort bucket edges by row, emit row_ptr + cv.
__global__ void place_kernel(const int* __restrict__ cur,
                             const int* __restrict__ boff,
                             const int2* __restrict__ tmp,
                             int* __restrict__ rpA, int* __restrict__ rpL,
                             int2* __restrict__ cvA, int2* __restrict__ cvL,
                             int n, int NB) {
    int b = blockIdx.x;  // 0..2*NB-1
    int m = (b >= NB) ? 1 : 0;
    int lb = b - m * NB;
    int r0 = lb * BRW;
    int r1 = min(r0 + BRW, n);
    int* rp = m ? rpL : rpA;
    int2* cv = m ? cvL : cvA;
    int lbase = m ? boff[NB] : 0;           // L's cv/rp offsets are local
    int p0 = boff[b] - lbase;
    __shared__ int cnt[BRW], curs[BRW], rbase[BRW];
    __shared__ int fill[8], fbase[9];
    __shared__ int2 stage[8 * SCAP];        // 2032 int2 = 16.3 KB
    int t = threadIdx.x;
    if (t < BRW) cnt[t] = 0;
    if (t < 8) {
        int k = b * 8 + t;
        int f = cur[k] - k * SSTRIDE;
        fill[t] = min(max(f, 0), SCAP);
    }
    __syncthreads();
    if (t == 0) {
        int r = 0;
#pragma unroll
        for (int i = 0; i < 8; ++i) { fbase[i] = r; r += fill[i]; }
        fbase[8] = r;
    }
    __syncthreads();
    int total = fbase[8];
    // coalesced per-segment load into stage + LDS row histogram
#pragma unroll
    for (int sg = 0; sg < 8; ++sg) {
        int f = fill[sg];
        const int2* src = tmp + (size_t)(b * 8 + sg) * SSTRIDE;
        int fb = fbase[sg];
        for (int i = t; i < f; i += 256) {
            int2 e = src[i];
            stage[fb + i] = e;
            atomicAdd(&cnt[(e.x >> 20) & 63], 1);
        }
    }
    __syncthreads();
    // exclusive scan over 64 row counts (wave 0, shfl ladder)
    if (t < 64) {
        int c = cnt[t];
        int sc = c;
#pragma unroll
        for (int off = 1; off < 64; off <<= 1) {
            int y = __shfl_up(sc, off, 64);
            if (t >= off) sc += y;
        }
        rbase[t] = sc - c;
        curs[t] = sc - c;
    }
    __syncthreads();
    if (t < r1 - r0) rp[r0 + t] = p0 + rbase[t];
    if (t == 0 && lb == NB - 1) rp[n] = p0 + total;  // sentinel
    __syncthreads();
    for (int i = t; i < total; i += 256) {
        int2 e = stage[i];
        int pos = atomicAdd(&curs[(e.x >> 20) & 63], 1);
        cv[p0 + pos] = make_int2(e.x & 0xFFFFF, e.y);
    }
}

// ---------------------------------------------------------------------------
// Fused GNN layer v4: one wave per row, quarter-wave float4 layout.
//   lane = 16q + ql; lane owns features [4ql, 4ql+4) (float4).
//   Quarter q walks edges p0+q, p0+q+4, ... -> one VMEM instr fetches FOUR
//   edge rows (1024 B/wave); unroll-4 per quarter = 16 rows in flight.
//   Matvec: quarter q covers k in [16q,16q+16), b128 LDS reads (stride 68).
//   (v3 row-pairing reverted: doubled working set thrashed L2 — R11.)
// ---------------------------------------------------------------------------
__global__ void fused_layer_kernel(const int* __restrict__ row_ptr,
                                   const int2* __restrict__ cv,
                                   const float* __restrict__ X,
                                   const float* __restrict__ W,
                                   float* __restrict__ Xn,
                                   float* __restrict__ s,
                                   const float* __restrict__ Wsv, int n) {
    __shared__ float Wt[64 * 68];       // Wt[k*68 + f] = W[f][k]; float4-aligned
    int tid = threadIdx.x;
    for (int i = tid; i < 4096; i += 256) {
        int j = i >> 6, k = i & 63;     // W[j,k] row-major
        Wt[k * 68 + j] = W[i];
    }
    __syncthreads();
    int lane = tid & 63;
    int ql = lane & 15;
    int q = lane >> 4;                  // quarter 0..3
    int wv = tid >> 6;
    float4 ws4 = {0.f, 0.f, 0.f, 0.f};
    if (s != nullptr) ws4 = *(const float4*)&Wsv[4 * ql];
    int nwaves = gridDim.x * 4;
    for (int row = blockIdx.x * 4 + wv; row < n; row += nwaves) {
        int p0 = row_ptr[row];
        int end = row_ptr[row + 1];
        // ---- gather: quarter-split edge streams, 4-deep unroll ----
        float4 a0 = {0.f, 0.f, 0.f, 0.f}, a1 = {0.f, 0.f, 0.f, 0.f};
        float4 a2 = {0.f, 0.f, 0.f, 0.f}, a3 = {0.f, 0.f, 0.f, 0.f};
        int p = p0 + q;
        for (; p + 12 < end; p += 16) {
            int2 e0 = cv[p], e1 = cv[p + 4], e2 = cv[p + 8], e3 = cv[p + 12];
            float4 x0 = *(const float4*)&X[(size_t)e0.x * 64 + 4 * ql];
            float4 x1 = *(const float4*)&X[(size_t)e1.x * 64 + 4 * ql];
            float4 x2 = *(const float4*)&X[(size_t)e2.x * 64 + 4 * ql];
            float4 x3 = *(const float4*)&X[(size_t)e3.x * 64 + 4 * ql];
            float v0 = __int_as_float(e0.y), v1 = __int_as_float(e1.y);
            float v2 = __int_as_float(e2.y), v3 = __int_as_float(e3.y);
            a0.x += v0 * x0.x; a0.y += v0 * x0.y; a0.z += v0 * x0.z; a0.w += v0 * x0.w;
            a1.x += v1 * x1.x; a1.y += v1 * x1.y; a1.z += v1 * x1.z; a1.w += v1 * x1.w;
            a2.x += v2 * x2.x; a2.y += v2 * x2.y; a2.z += v2 * x2.z; a2.w += v2 * x2.w;
            a3.x += v3 * x3.x; a3.y += v3 * x3.y; a3.z += v3 * x3.z; a3.w += v3 * x3.w;
        }
        for (; p < end; p += 4) {
            int2 e = cv[p];
            float4 x = *(const float4*)&X[(size_t)e.x * 64 + 4 * ql];
            float v = __int_as_float(e.y);
            a0.x += v * x.x; a0.y += v * x.y; a0.z += v * x.z; a0.w += v * x.w;
        }
        float4 acc;
        acc.x = (a0.x + a1.x) + (a2.x + a3.x);
        acc.y = (a0.y + a1.y) + (a2.y + a3.y);
        acc.z = (a0.z + a1.z) + (a2.z + a3.z);
        acc.w = (a0.w + a1.w) + (a2.w + a3.w);
        // combine quarters: all lanes with same ql hold full AX[4ql..4ql+4)
        acc.x += __shfl_xor(acc.x, 32, 64); acc.x += __shfl_xor(acc.x, 16, 64);
        acc.y += __shfl_xor(acc.y, 32, 64); acc.y += __shfl_xor(acc.y, 16, 64);
        acc.z += __shfl_xor(acc.z, 32, 64); acc.z += __shfl_xor(acc.z, 16, 64);
        acc.w += __shfl_xor(acc.w, 32, 64); acc.w += __shfl_xor(acc.w, 16, 64);
        // ---- matvec: quarter q covers k in [16q, 16q+16) ----
        float4 h4 = {0.f, 0.f, 0.f, 0.f};
        int kbase = 16 * q;
#pragma unroll
        for (int kk = 0; kk < 16; kk += 4) {
            int k = kbase + kk;
            int src = k >> 2;                       // lane holding acc[k..k+4)
            float b0 = __shfl(acc.x, src, 64);      // acc[k]
            float b1 = __shfl(acc.y, src, 64);      // acc[k+1]
            float b2 = __shfl(acc.z, src, 64);      // acc[k+2]
            float b3 = __shfl(acc.w, src, 64);      // acc[k+3]
            float4 w0 = *(const float4*)&Wt[(k + 0) * 68 + 4 * ql];
            float4 w1 = *(const float4*)&Wt[(k + 1) * 68 + 4 * ql];
            float4 w2 = *(const float4*)&Wt[(k + 2) * 68 + 4 * ql];
            float4 w3 = *(const float4*)&Wt[(k + 3) * 68 + 4 * ql];
            h4.x += b0 * w0.x + b1 * w1.x + b2 * w2.x + b3 * w3.x;
            h4.y += b0 * w0.y + b1 * w1.y + b2 * w2.y + b3 * w3.y;
            h4.z += b0 * w0.z + b1 * w1.z + b2 * w2.z + b3 * w3.z;
            h4.w += b0 * w0.w + b1 * w1.w + b2 * w2.w + b3 * w3.w;
        }
        h4.x += __shfl_xor(h4.x, 32, 64); h4.x += __shfl_xor(h4.x, 16, 64);
        h4.y += __shfl_xor(h4.y, 32, 64); h4.y += __shfl_xor(h4.y, 16, 64);
        h4.z += __shfl_xor(h4.z, 32, 64); h4.z += __shfl_xor(h4.z, 16, 64);
        h4.w += __shfl_xor(h4.w, 32, 64); h4.w += __shfl_xor(h4.w, 16, 64);
        // ---- residual + store (quarter 0 writes) + folded score ----
        float4 xv = *(const float4*)&X[(size_t)row * 64 + 4 * ql];
        float4 o;
        o.x = xv.x + fmaxf(h4.x, 0.f);
        o.y = xv.y + fmaxf(h4.y, 0.f);
        o.z = xv.z + fmaxf(h4.z, 0.f);
        o.w = xv.w + fmaxf(h4.w, 0.f);
        if (q == 0) *(float4*)&Xn[(size_t)row * 64 + 4 * ql] = o;
        if (s != nullptr) {
            float d = o.x * ws4.x + o.y * ws4.y + o.z * ws4.z + o.w * ws4.w;
#pragma unroll
            for (int off = 8; off; off >>= 1) d += __shfl_down(d, off, 16);
            if (lane == 0) s[row] = d;
        }
    }
}

// ---------------------------------------------------------------------------
// Fused power iteration v3: 4 lanes per row, 4-deep independent load chains.
// Per-iteration launch (coop grid.sync measured ~134us/iter -> never).
// ---------------------------------------------------------------------------
__global__ void power_iter_kernel(const int* __restrict__ row_ptr,
                                  const int2* __restrict__ cv,
                                  const float* __restrict__ v_in,
                                  float* __restrict__ v_out,
                                  const float* __restrict__ norm_prev,  // 64 slots or null
                                  float* __restrict__ norm_out,         // 64 slots
                                  int n) {
    int lane = threadIdx.x & 63;
    float scale = 1.f;
    if (norm_prev) {
        float x = norm_prev[lane];
#pragma unroll
        for (int off = 32; off; off >>= 1) x += __shfl_xor(x, off, 64);
        scale = 1.f / fmaxf(sqrtf(x), 1e-12f);
    }
    int g = blockIdx.x * 256 + threadIdx.x;
    int row = g >> 2;
    int t = g & 3;
    float sq = 0.f;
    if (row < n) {
        int p = row_ptr[row] + t;
        int end = row_ptr[row + 1];
        float s0 = 0.f, s1 = 0.f, s2 = 0.f, s3 = 0.f;
        for (; p + 12 < end; p += 16) {
            int2 e0 = cv[p], e1 = cv[p + 4], e2 = cv[p + 8], e3 = cv[p + 12];
            s0 += __int_as_float(e0.y) * v_in[e0.x];
            s1 += __int_as_float(e1.y) * v_in[e1.x];
            s2 += __int_as_float(e2.y) * v_in[e2.x];
            s3 += __int_as_float(e3.y) * v_in[e3.x];
        }
        for (; p < end; p += 4) {
            int2 e = cv[p];
            s0 += __int_as_float(e.y) * v_in[e.x];
        }
        float sv = (s0 + s1) + (s2 + s3);
        sv += __shfl_xor(sv, 2, 4);
        sv += __shfl_xor(sv, 1, 4);
        if (t == 0) {
            float sg = (sv > 0.f) ? 1.f : ((sv < 0.f) ? -1.f : 0.f);
            float w = sv * scale - TAU * sg;
            v_out[row] = w;
            sq = w * w;
        }
    }
    for (int off = 32; off; off >>= 1) sq += __shfl_down(sq, off, 64);
    __shared__ float sh[4];
    int wv = threadIdx.x >> 6;
    if (lane == 0) sh[wv] = sq;
    __syncthreads();
    if (threadIdx.x == 0)
        atomicAdd(&norm_out[blockIdx.x & 63], sh[0] + sh[1] + sh[2] + sh[3]);
}

__global__ void finalize_kernel(const float* __restrict__ v,
                                const float* __restrict__ slots,
                                float* __restrict__ out, int n) {
    int lane = threadIdx.x & 63;
    float x = slots[lane];
#pragma unroll
    for (int off = 32; off; off >>= 1) x += __shfl_xor(x, off, 64);
    float inv = 1.f / fmaxf(sqrtf(x), 1e-12f);
    int i = blockIdx.x * 256 + threadIdx.x;
    if (i < n) out[i] = v[i] * inv;
}

extern "C" void kernel_launch(void* const* d_in, const int* in_sizes, int n_in,
                              void* d_out, int out_size, void* d_ws, size_t ws_size,
                              hipStream_t stream) {
    const int* A_row = (const int*)d_in[0];
    const int* A_col = (const int*)d_in[1];
    const float* A_val = (const float*)d_in[2];
    const int* L_row = (const int*)d_in[3];
    const int* L_col = (const int*)d_in[4];
    const float* L_val = (const float*)d_in[5];
    const float* embed = (const float*)d_in[6];
    const float* W1 = (const float*)d_in[7];
    const float* W2 = (const float*)d_in[8];
    const float* Ws = (const float*)d_in[9];
    float* out = (float*)d_out;

    const int E = in_sizes[0];
    const int D = 64;
    const int N = in_sizes[6] / D;
    const int ITERS = 10;
    const int NB = (N + BRW - 1) / BRW;   // buckets per matrix (1563)
    const int NB2 = 2 * NB;
    const int K = NB2 * 8;                // segment cursors

    char* ws = (char*)d_ws;
    size_t off = 0;
    auto carve = [&](size_t bytes) {
        void* p = ws + off;
        off += (bytes + 255) & ~(size_t)255;
        return p;
    };
    size_t feat_bytes = (size_t)N * D * sizeof(float);
    size_t tmp_bytes = (size_t)K * SSTRIDE * sizeof(int2);
    // X0/X1 and tmp share one region (tmp dead once place ran; X live after)
    char* base = (char*)carve(tmp_bytes > 2 * feat_bytes ? tmp_bytes : 2 * feat_bytes);
    float* X0 = (float*)base;
    float* X1 = (float*)(base + feat_bytes);
    int2* tmp = (int2*)base;
    int* A_rp = (int*)carve((size_t)(N + 1) * sizeof(int));
    int2* A_cv = (int2*)carve((size_t)E * sizeof(int2));
    int* L_rp = (int*)carve((size_t)(N + 1) * sizeof(int));
    int2* L_cv = (int2*)carve((size_t)E * sizeof(int2));
    int* cur = (int*)carve((size_t)K * sizeof(int));
    int* boff = (int*)carve((size_t)NB2 * sizeof(int));
    float* v_cur = (float*)carve((size_t)N * sizeof(float));
    float* v_new = (float*)carve((size_t)N * sizeof(float));
    float* norms = (float*)carve((size_t)ITERS * 64 * sizeof(float));

    int e_blocks = (E + 255) / 256;

    // ---- CSR build: XCD-local binned sort (per-matrix bin for L2 fit) ----
    init_kernel<<<(K + 255) / 256, 256, 0, stream>>>(cur, norms, K, ITERS * 64);
    bin_kernel<<<e_blocks, 256, 0, stream>>>(A_row, A_col, A_val, cur, tmp, E, 0);
    bin_kernel<<<e_blocks, 256, 0, stream>>>(L_row, L_col, L_val, cur, tmp, E, NB);
    scan_fused_kernel<<<1, 1024, 0, stream>>>(cur, boff, NB2);
    place_kernel<<<NB2, 256, 0, stream>>>(cur, boff, tmp,
                                          A_rp, L_rp, A_cv, L_cv, N, NB);

    // ---- two fused residual GNN layers (layer 2 also emits scores) ----
    int fl_blocks = 2048;
    fused_layer_kernel<<<fl_blocks, 256, 0, stream>>>(
        A_rp, A_cv, embed, W1, X0, nullptr, Ws, N);
    fused_layer_kernel<<<fl_blocks, 256, 0, stream>>>(
        A_rp, A_cv, X0, W2, X1, v_cur, Ws, N);

    // ---- power iterations (normalize folded; 64-slot norm partials) ----
    int p_blocks = (N * 4 + 255) / 256;
    int n_blocks = (N + 255) / 256;
    float* cur_v = v_cur;
    float* nxt_v = v_new;
    for (int it = 0; it < ITERS; ++it) {
        power_iter_kernel<<<p_blocks, 256, 0, stream>>>(
            L_rp, L_cv, cur_v, nxt_v,
            it ? (norms + (it - 1) * 64) : nullptr, norms + it * 64, N);
        float* t = cur_v; cur_v = nxt_v; nxt_v = t;
    }
    finalize_kernel<<<n_blocks, 256, 0, stream>>>(cur_v, norms + (ITERS - 1) * 64, out, N);
}